// Round 8
// baseline (367.977 us; speedup 1.0000x reference)
//
#include <hip/hip_runtime.h>
#include <hip/hip_bf16.h>

#define N_ 32
#define C_ 128
#define H_ 48
#define W_ 48
#define P_ (H_*W_)   // 2304
#define K_ 64
#define S_ 4
#define L_ 3
#define R_ 21
#define NB_ 72       // P_/32 pixel tiles per image
#define M_ 512       // total logit rows
#define CH_ 18       // vlad chunks (128 px each)
#define PT_ 3        // pixel tiles per k_gemm block
#define GB_ (NB_/PT_)// 24

typedef __hip_bfloat16 bf16;
typedef __attribute__((ext_vector_type(8))) short   bf16x8;
typedef __attribute__((ext_vector_type(8))) unsigned short u16x8;
typedef __attribute__((ext_vector_type(4))) float   f32x4;

__device__ __forceinline__ float b2f(bf16 v){ return __bfloat162float(v); }
__device__ __forceinline__ float u2f(unsigned short u){
  union { unsigned i; float f; } v; v.i = ((unsigned)u) << 16; return v.f;
}
__device__ __forceinline__ unsigned short f2u(float f){
  bf16 h = __float2bfloat16(f);
  return *(unsigned short*)&h;
}

// wave-uniform dtype probe: 1 if x is fp32, 0 if bf16. Reads fixed 1024-elem window.
// fp32 reinterpreted as u16: low halves are mantissa bits -> ~44% have bf16-exp >= 0x8E
// (|v| >= 2^15, impossible for N(0,1) bf16). Expected popcount: ~63 (fp32) vs 0 (bf16).
__device__ __forceinline__ int is_f32(const unsigned short* __restrict__ xb){
  int lane = threadIdx.x & 63;
  int w = 0;
  #pragma unroll
  for (int i=0;i<16;++i){
    int e = (xb[lane*16 + i] >> 7) & 0xFF;
    w += (e >= 0x8E) ? 1 : 0;
  }
  unsigned long long b = __ballot(w > 0);
  return __popcll(b) > 32;
}

// ---------- K0: build Wall[512][128] bf16 + zero sal ----------
__global__ __launch_bounds__(256) void k_wall(const void* __restrict__ cvw, const void* __restrict__ csw,
                                              const void* __restrict__ caw, const void* __restrict__ x,
                                              bf16* __restrict__ Wall, float* __restrict__ sal){
  int f32 = is_f32((const unsigned short*)x);
  int i = blockIdx.x*256 + threadIdx.x;
  float v;
  if (i < 8192)       v = f32 ? ((const float*)cvw)[i]        : b2f(((const bf16*)cvw)[i]);
  else if (i < 40960) v = f32 ? ((const float*)csw)[i-8192]   : b2f(((const bf16*)csw)[i-8192]);
  else                v = f32 ? ((const float*)caw)[i-40960]  : b2f(((const bf16*)caw)[i-40960]);
  Wall[i] = __float2bfloat16(v);
  if (i < N_*K_*R_) sal[i] = 0.f;
}

// ---------- K1: L2 norm, 2 pixels/thread -> xnT[n][p][c] and xnC[n][c][p] ----------
__global__ __launch_bounds__(256) void k_norm(const void* __restrict__ x,
                                              bf16* __restrict__ xnT,
                                              bf16* __restrict__ xnC){
  int f32 = is_f32((const unsigned short*)x);
  int idx = blockIdx.x*256 + threadIdx.x;        // pair index: n*(P/2) + q
  int n = idx / (P_/2), q = idx - n*(P_/2);
  int p = q*2;
  float ss0 = 0.f, ss1 = 0.f;
  bf16* xo0 = xnT + ((size_t)n*P_ + p)*C_;
  bf16* xo1 = xo0 + C_;
  unsigned* xq = (unsigned*)(xnC + (size_t)n*C_*P_ + p);   // stride P_/2 u32
  if (f32){
    const float* xc = (const float*)x + (size_t)n*C_*P_ + p;
    #pragma unroll 8
    for (int c=0;c<C_;++c){
      float2 v = *(const float2*)(xc + (size_t)c*P_);
      ss0 += v.x*v.x; ss1 += v.y*v.y;
    }
    float i0 = 1.f/fmaxf(sqrtf(ss0),1e-12f), i1 = 1.f/fmaxf(sqrtf(ss1),1e-12f);
    for (int c8=0;c8<C_;c8+=8){
      u16x8 pk0, pk1;
      #pragma unroll
      for (int j=0;j<8;++j){
        float2 v = *(const float2*)(xc + (size_t)(c8+j)*P_);
        unsigned short a0 = f2u(v.x*i0), a1 = f2u(v.y*i1);
        pk0[j]=a0; pk1[j]=a1;
        xq[(size_t)(c8+j)*(P_/2)] = (unsigned)a0 | ((unsigned)a1<<16);
      }
      *(u16x8*)(xo0+c8) = pk0; *(u16x8*)(xo1+c8) = pk1;
    }
  } else {
    const unsigned* xc = (const unsigned*)((const bf16*)x + (size_t)n*C_*P_ + p);
    #pragma unroll 8
    for (int c=0;c<C_;++c){
      unsigned v = xc[(size_t)c*(P_/2)];
      float v0 = u2f(v&0xffff), v1 = u2f(v>>16);
      ss0 += v0*v0; ss1 += v1*v1;
    }
    float i0 = 1.f/fmaxf(sqrtf(ss0),1e-12f), i1 = 1.f/fmaxf(sqrtf(ss1),1e-12f);
    for (int c8=0;c8<C_;c8+=8){
      u16x8 pk0, pk1;
      #pragma unroll
      for (int j=0;j<8;++j){
        unsigned v = xc[(size_t)(c8+j)*(P_/2)];
        unsigned short a0 = f2u(u2f(v&0xffff)*i0), a1 = f2u(u2f(v>>16)*i1);
        pk0[j]=a0; pk1[j]=a1;
        xq[(size_t)(c8+j)*(P_/2)] = (unsigned)a0 | ((unsigned)a1<<16);
      }
      *(u16x8*)(xo0+c8) = pk0; *(u16x8*)(xo1+c8) = pk1;
    }
  }
}

// ---------- K2: fused 512-row MFMA GEMM over 3 pixel tiles; A-frags cached in regs ----------
// grid (GB_=24, N_=32), 4 waves. Wave w owns rows [w*128, w*128+128).
__global__ __launch_bounds__(256, 2) void k_gemm(const bf16* __restrict__ Wall,
                                                 const bf16* __restrict__ xnT,
                                                 unsigned short* __restrict__ a,
                                                 float* __restrict__ sal){
  __shared__ __align__(16) char smem[320*34*4];            // 43520 B; reused as appS
  float (*ldsL)[34] = (float(*)[34])smem;                  // [320][34]
  unsigned short (*appS)[36] = (unsigned short(*)[36])smem;// [192][36] = 13824 B
  __shared__ float redA[32][8];
  __shared__ float redB[32][8];
  __shared__ __align__(16) unsigned short a_tile[K_*32];
  int n = blockIdx.y, pg = blockIdx.x;
  int t = threadIdx.x, wv = t>>6, l = t&63;
  int mrow = l&15, quad = l>>4;

  // ---- A fragments: load once, reuse for all PT_ tiles (32 x bf16x8 = 128 VGPRs) ----
  const bf16* Abase = Wall + ((size_t)(wv*128 + mrow))*C_ + quad*8;
  bf16x8 Afr[8][4];
  #pragma unroll
  for (int rt=0;rt<8;++rt)
    #pragma unroll
    for (int ks=0;ks<4;++ks)
      Afr[rt][ks] = *(const bf16x8*)(Abase + (size_t)rt*16*C_ + ks*32);

  for (int pt=0; pt<PT_; ++pt){
    int pb = pg*PT_ + pt;
    int p0 = pb*32;
    const bf16* Bbase = xnT + ((size_t)n*P_ + p0 + mrow)*C_ + quad*8;

    f32x4 acc[8][2];
    #pragma unroll
    for (int rt=0;rt<8;++rt){ acc[rt][0] = (f32x4){0,0,0,0}; acc[rt][1] = (f32x4){0,0,0,0}; }

    #pragma unroll
    for (int ks=0;ks<4;++ks){
      bf16x8 b0 = *(const bf16x8*)(Bbase + ks*32);
      bf16x8 b1 = *(const bf16x8*)(Bbase + 16*C_ + ks*32);
      #pragma unroll
      for (int rt=0;rt<8;++rt){
        acc[rt][0] = __builtin_amdgcn_mfma_f32_16x16x32_bf16(Afr[rt][ks], b0, acc[rt][0], 0,0,0);
        acc[rt][1] = __builtin_amdgcn_mfma_f32_16x16x32_bf16(Afr[rt][ks], b1, acc[rt][1], 0,0,0);
      }
    }
    // C/D: col = lane&15, row = quad*4 + reg. Rows <320 -> LDS; app rows stay in regs.
    #pragma unroll
    for (int rt=0;rt<8;++rt){
      int row0 = wv*128 + rt*16;
      if (row0 < 320){
        #pragma unroll
        for (int ct=0;ct<2;++ct)
          #pragma unroll
          for (int r=0;r<4;++r)
            ldsL[row0 + quad*4 + r][ct*16 + mrow] = acc[rt][ct][r];
      }
    }
    __syncthreads();

    // ---- softmax: thread t -> pixel px = t&31, cluster group g2 = t>>5 ----
    int px = t&31, g2 = t>>5;
    float sc[8];
    #pragma unroll
    for (int kk=0;kk<8;++kk) sc[kk] = ldsL[g2*8+kk][px];
    float pm = sc[0];
    #pragma unroll
    for (int kk=1;kk<8;++kk) pm = fmaxf(pm, sc[kk]);
    redA[px][g2] = pm;
    __syncthreads();
    float m = redA[px][0];
    #pragma unroll
    for (int i=1;i<8;++i) m = fmaxf(m, redA[px][i]);
    float ps = 0.f;
    #pragma unroll
    for (int kk=0;kk<8;++kk) ps += __expf(sc[kk]-m);
    redB[px][g2] = ps;
    __syncthreads();
    float Z = 0.f;
    #pragma unroll
    for (int i=0;i<8;++i) Z += redB[px][i];
    float invZ = 1.f / Z;

    #pragma unroll
    for (int kk=0;kk<8;++kk){
      int k = g2*8 + kk;
      float s0 = sc[kk];
      float sh0 = ldsL[64 + k*4 + 0][px];
      float sh1 = ldsL[64 + k*4 + 1][px];
      float sh2 = ldsL[64 + k*4 + 2][px];
      float sh3 = ldsL[64 + k*4 + 3][px];
      float m2 = fmaxf(fmaxf(fmaxf(fmaxf(s0, sh0), sh1), sh2), sh3);
      float e0 = __expf(s0-m2);
      float den = e0 + __expf(sh0-m2) + __expf(sh1-m2) + __expf(sh2-m2) + __expf(sh3-m2);
      a_tile[k*32 + px] = f2u(__expf(s0-m)*invZ * (e0/den));
    }
    __syncthreads();   // all ldsL reads done; a_tile complete

    size_t tile = (size_t)n*NB_ + pb;
    *(u16x8*)(a + tile*(K_*32) + t*8) = ((const u16x8*)a_tile)[t];

    // ---- app rows (relu, bf16) -> appS (overlays ldsL) ----
    #pragma unroll
    for (int rt=0;rt<8;++rt){
      int row0 = wv*128 + rt*16;
      if (row0 >= 320){
        int ar0 = row0 - 320 + quad*4;
        #pragma unroll
        for (int ct=0;ct<2;++ct)
          #pragma unroll
          for (int r=0;r<4;++r)
            appS[ar0 + r][ct*16 + mrow] = f2u(fmaxf(acc[rt][ct][r], 0.f));
      }
    }
    __syncthreads();

    // ---- region sums: wave handles a level-slice for its k = t&63; atomicAdd to sal ----
    int qsel = wv, k = t&63;
    int rowbase = (qsel==0) ? k : (qsel==1 ? 64+k : 128+k);
    const unsigned* aps = (const unsigned*)&appS[rowbase][0];
    float racc[8];
    #pragma unroll
    for (int r=0;r<8;++r) racc[r] = 0.f;
    #pragma unroll
    for (int e=0;e<16;++e){
      unsigned pr = aps[e];
      #pragma unroll
      for (int half=0;half<2;++half){
        float v = u2f(half ? (unsigned short)(pr>>16) : (unsigned short)(pr&0xffff));
        int p = p0 + 2*e + half;
        int h = p/48, wc = p - h*48;
        if (qsel == 0){
          racc[0] += v;
        } else if (qsel == 1){
          bool hA = h < 32, hB = h >= 16;
          bool wA = wc < 32, wB = wc >= 16;
          racc[0] += (hA&&wA)?v:0.f; racc[1] += (hA&&wB)?v:0.f;
          racc[2] += (hB&&wA)?v:0.f; racc[3] += (hB&&wB)?v:0.f;
        } else {
          int i0 = (qsel==2)?0:2;
          bool hA = (h>=10*i0-1)&&(h<10*i0+19);
          bool hB = (h>=10*(i0+1)-1)&&(h<10*(i0+1)+19);
          #pragma unroll
          for (int j=0;j<4;++j){
            bool wj = (wc>=10*j-1)&&(wc<10*j+19);
            racc[j]   += (hA&&wj)?v:0.f;
            racc[4+j] += (hB&&wj)?v:0.f;
          }
        }
      }
    }
    float* sp = sal + (size_t)n*K_*R_ + k*R_;
    if (qsel == 0){
      atomicAdd(&sp[0], racc[0]);
    } else if (qsel == 1){
      #pragma unroll
      for (int r=0;r<4;++r) atomicAdd(&sp[1+r], racc[r]);
    } else if (qsel == 2){
      #pragma unroll
      for (int r=0;r<8;++r) atomicAdd(&sp[5+r], racc[r]);
    } else {
      #pragma unroll
      for (int r=0;r<8;++r) atomicAdd(&sp[13+r], racc[r]);
    }
    __syncthreads();   // LDS (appS/ldsL) reused next tile
  }
}

// ---------- K3: vlad partials via MFMA. Block = (chunk of 128 px, n). ----------
__global__ __launch_bounds__(256) void k_vlad(const bf16* __restrict__ xnC,
                                              const unsigned short* __restrict__ a,
                                              const float* __restrict__ sal,
                                              float* __restrict__ vladPart,
                                              float* __restrict__ sumawPart){
  __shared__ float s_sal[K_][R_];                    // 5376 B
  __shared__ __align__(16) unsigned short awL[4][K_][40];  // 20480 B
  __shared__ float s_part[4][K_];                    // 1024 B
  int chunk = blockIdx.x, n = blockIdx.y, t = threadIdx.x;
  int p0 = chunk*128;
  for (int i=t;i<K_*R_;i+=256) ((float*)s_sal)[i] = sal[(size_t)n*K_*R_ + i];
  __syncthreads();

  {
    int pxl = t & 127, khalf = t>>7;
    int pbl = pxl>>5, px = pxl&31;
    int p = p0 + pxl;
    int h = p/48, wc = p - h*48;
    bool h1[2], w1[2], h2[4], w2[4];
    #pragma unroll
    for (int i=0;i<2;++i){ h1[i] = (h>=16*i)&&(h<16*i+32); w1[i] = (wc>=16*i)&&(wc<16*i+32); }
    #pragma unroll
    for (int i=0;i<4;++i){ h2[i] = (h>=10*i-1)&&(h<10*i+19); w2[i] = (wc>=10*i-1)&&(wc<10*i+19); }
    const unsigned short* at = a + ((size_t)(n*NB_ + chunk*4 + pbl)*K_)*32 + px;
    #pragma unroll 4
    for (int kk=0;kk<32;++kk){
      int k = khalf*32 + kk;
      float w = s_sal[k][0];
      #pragma unroll
      for (int i=0;i<2;++i) if (h1[i])
        #pragma unroll
        for (int j=0;j<2;++j) if (w1[j]) w += s_sal[k][1+2*i+j];
      #pragma unroll
      for (int i=0;i<4;++i) if (h2[i])
        #pragma unroll
        for (int j=0;j<4;++j) if (w2[j]) w += s_sal[k][5+4*i+j];
      awL[pbl][k][px] = f2u(u2f(at[k*32]) * w);
    }
  }
  __syncthreads();
  {
    int k = t&63, qr = t>>6;
    float s = 0.f;
    #pragma unroll 8
    for (int j=0;j<32;++j) s += u2f(awL[qr][k][j]);
    s_part[qr][k] = s;
  }
  __syncthreads();

  int wv = t>>6, l = t&63, mrow = l&15, quad = l>>4;
  f32x4 acc[4][2];
  #pragma unroll
  for (int mt=0;mt<4;++mt){ acc[mt][0] = (f32x4){0,0,0,0}; acc[mt][1] = (f32x4){0,0,0,0}; }
  const bf16* Bb = xnC + ((size_t)n*C_ + wv*32 + mrow)*P_ + p0 + quad*8;
  #pragma unroll
  for (int ks=0;ks<4;++ks){
    bf16x8 b0 = *(const bf16x8*)(Bb + ks*32);
    bf16x8 b1 = *(const bf16x8*)(Bb + (size_t)16*P_ + ks*32);
    #pragma unroll
    for (int mt=0;mt<4;++mt){
      bf16x8 af = *(const bf16x8*)((const bf16*)&awL[ks][mt*16 + mrow][quad*8]);
      acc[mt][0] = __builtin_amdgcn_mfma_f32_16x16x32_bf16(af, b0, acc[mt][0], 0,0,0);
      acc[mt][1] = __builtin_amdgcn_mfma_f32_16x16x32_bf16(af, b1, acc[mt][1], 0,0,0);
    }
  }
  float* vp = vladPart + ((size_t)(n*CH_ + chunk))*(K_*C_);
  #pragma unroll
  for (int mt=0;mt<4;++mt){
    #pragma unroll
    for (int ct=0;ct<2;++ct){
      int c = wv*32 + ct*16 + mrow;
      #pragma unroll
      for (int r=0;r<4;++r){
        int k = mt*16 + quad*4 + r;
        vp[k*C_ + c] = acc[mt][ct][r];
      }
    }
  }
  if (t < K_)
    sumawPart[((size_t)n*CH_ + chunk)*K_ + t] = s_part[0][t]+s_part[1][t]+s_part[2][t]+s_part[3][t];
}

// ---------- K4: chunk reduce + centroid + intra-norm * clw + global norm + store ----------
__global__ __launch_bounds__(256) void k_final(const float* __restrict__ vladPart,
                                               const float* __restrict__ sumawPart,
                                               const void* __restrict__ cen,
                                               const void* __restrict__ clw,
                                               const void* __restrict__ x,
                                               void* __restrict__ out){
  __shared__ float s_v[K_*C_];
  __shared__ float s_sumaw[K_];
  __shared__ float s_ssk[K_];
  __shared__ float s_scale[K_];
  __shared__ float s_gs;
  int n = blockIdx.x, t = threadIdx.x;
  int f32 = is_f32((const unsigned short*)x);
  if (t < K_){
    float s = 0.f;
    #pragma unroll
    for (int ch=0;ch<CH_;++ch) s += sumawPart[((size_t)n*CH_ + ch)*K_ + t];
    s_sumaw[t] = s;
  }
  __syncthreads();
  const float* vp = vladPart + (size_t)n*CH_*(K_*C_);
  for (int i=t;i<K_*C_;i+=256){
    float v = 0.f;
    #pragma unroll
    for (int ch=0;ch<CH_;++ch) v += vp[(size_t)ch*(K_*C_) + i];
    float cv = f32 ? ((const float*)cen)[i] : b2f(((const bf16*)cen)[i]);
    s_v[i] = v - cv * s_sumaw[i>>7];
  }
  __syncthreads();
  int k = t >> 2, q = t & 3;
  float ss = 0.f;
  for (int mm=0;mm<32;++mm){ float v = s_v[k*C_ + q + 4*mm]; ss += v*v; }
  ss += __shfl_down(ss, 2);
  ss += __shfl_down(ss, 1);
  if (q == 0) s_ssk[k] = ss;
  __syncthreads();
  if (t < K_){
    float cw = f32 ? ((const float*)clw)[t] : b2f(((const bf16*)clw)[t]);
    s_scale[t] = cw / fmaxf(sqrtf(s_ssk[t]), 1e-12f);
  }
  __syncthreads();
  if (t == 0){
    float gss = 0.f;
    for (int kk=0;kk<K_;++kk) gss += s_ssk[kk]*s_scale[kk]*s_scale[kk];
    s_gs = 1.f / fmaxf(sqrtf(gss), 1e-12f);
  }
  __syncthreads();
  float gsc = s_gs;
  if (f32){
    float* op = (float*)out + (size_t)n*K_*C_;
    for (int i=t;i<K_*C_;i+=256) op[i] = s_v[i]*s_scale[i>>7]*gsc;
  } else {
    bf16* op = (bf16*)out + (size_t)n*K_*C_;
    for (int i=t;i<K_*C_;i+=256) op[i] = __float2bfloat16(s_v[i]*s_scale[i>>7]*gsc);
  }
}

extern "C" void kernel_launch(void* const* d_in, const int* in_sizes, int n_in,
                              void* d_out, int out_size, void* d_ws, size_t ws_size,
                              hipStream_t stream){
  const void* x   = d_in[0];
  const void* cen = d_in[1];
  const void* cvw = d_in[2];
  const void* csw = d_in[3];
  const void* caw = d_in[4];
  const void* clw = d_in[5];

  char* ws = (char*)d_ws;
  bf16* Wall  = (bf16*)ws;             ws += (size_t)M_*C_*2;        // 128 KB
  bf16* xnT   = (bf16*)ws;             ws += (size_t)N_*P_*C_*2;     // 18.87 MB
  bf16* xnC   = (bf16*)ws;             ws += (size_t)N_*C_*P_*2;     // 18.87 MB
  unsigned short* a = (unsigned short*)ws;  ws += (size_t)N_*K_*P_*2;// 9.44 MB (tiled)
  float* sal  = (float*)ws;            ws += (size_t)N_*K_*R_*4;     // 0.17 MB
  float* vladPart  = (float*)ws;       ws += (size_t)N_*CH_*K_*C_*4; // 18.87 MB
  float* sumawPart = (float*)ws;       ws += (size_t)N_*CH_*K_*4;    // 0.147 MB

  k_wall  <<<dim3(M_*C_/256),   256, 0, stream>>>(cvw, csw, caw, x, Wall, sal);
  k_norm  <<<dim3(N_*P_/2/256), 256, 0, stream>>>(x, xnT, xnC);
  k_gemm  <<<dim3(GB_, N_),     256, 0, stream>>>(Wall, xnT, a, sal);
  k_vlad  <<<dim3(CH_, N_),     256, 0, stream>>>(xnC, a, sal, vladPart, sumawPart);
  k_final <<<dim3(N_),          256, 0, stream>>>(vladPart, sumawPart, cen, clw, x, d_out);
}

// Round 9
// 236.552 us; speedup vs baseline: 1.5556x; 1.5556x over previous
//
#include <hip/hip_runtime.h>
#include <hip/hip_bf16.h>

#define N_ 32
#define C_ 128
#define H_ 48
#define W_ 48
#define P_ (H_*W_)   // 2304
#define K_ 64
#define S_ 4
#define L_ 3
#define R_ 21
#define NB_ 72       // P_/32 pixel tiles per image
#define M_ 512       // total logit rows
#define CH_ 9        // vlad chunks (256 px each)

typedef __hip_bfloat16 bf16;
typedef __attribute__((ext_vector_type(8))) short   bf16x8;
typedef __attribute__((ext_vector_type(8))) unsigned short u16x8;
typedef __attribute__((ext_vector_type(4))) float   f32x4;

__device__ __forceinline__ float b2f(bf16 v){ return __bfloat162float(v); }
__device__ __forceinline__ float u2f(unsigned short u){
  union { unsigned i; float f; } v; v.i = ((unsigned)u) << 16; return v.f;
}
__device__ __forceinline__ unsigned short f2u(float f){
  bf16 h = __float2bfloat16(f);
  return *(unsigned short*)&h;
}

// wave-uniform dtype probe: 1 if x is fp32, 0 if bf16 (reads fixed 1024-elem window).
__device__ __forceinline__ int is_f32(const unsigned short* __restrict__ xb){
  int lane = threadIdx.x & 63;
  int w = 0;
  #pragma unroll
  for (int i=0;i<16;++i){
    int e = (xb[lane*16 + i] >> 7) & 0xFF;
    w += (e >= 0x8E) ? 1 : 0;
  }
  unsigned long long b = __ballot(w > 0);
  return __popcll(b) > 32;
}

// ---------- K0: build Wall[512][128] bf16 ----------
__global__ __launch_bounds__(256) void k_wall(const void* __restrict__ cvw, const void* __restrict__ csw,
                                              const void* __restrict__ caw, const void* __restrict__ x,
                                              bf16* __restrict__ Wall){
  int f32 = is_f32((const unsigned short*)x);
  int i = blockIdx.x*256 + threadIdx.x;
  float v;
  if (i < 8192)       v = f32 ? ((const float*)cvw)[i]        : b2f(((const bf16*)cvw)[i]);
  else if (i < 40960) v = f32 ? ((const float*)csw)[i-8192]   : b2f(((const bf16*)csw)[i-8192]);
  else                v = f32 ? ((const float*)caw)[i-40960]  : b2f(((const bf16*)caw)[i-40960]);
  Wall[i] = __float2bfloat16(v);
}

// ---------- K1: L2 norm via LDS transpose; fully coalesced writes of xnT and xnC ----------
// block = 128 pixels; thread t: px = t&127, owns 64 channels (ch half = t>>7) in VGPRs.
__global__ __launch_bounds__(256) void k_norm(const void* __restrict__ x,
                                              bf16* __restrict__ xnT,
                                              bf16* __restrict__ xnC){
  __shared__ float sred[2][128];
  __shared__ unsigned short tile[128][130];      // [c][px], pad 130 (33.3 KB)
  int f32 = is_f32((const unsigned short*)x);
  int bi = blockIdx.x;
  int n = bi / (P_/128), tb = bi % (P_/128);
  int p0 = tb*128;
  int t = threadIdx.x, px = t&127, ch = t>>7, c0 = ch*64;

  float vals[64];
  float ss = 0.f;
  if (f32){
    const float* xb = (const float*)x + ((size_t)n*C_ + c0)*P_ + p0 + px;
    #pragma unroll
    for (int j=0;j<64;++j){ float v = xb[(size_t)j*P_]; vals[j] = v; ss += v*v; }
  } else {
    const unsigned short* xb = (const unsigned short*)x + ((size_t)n*C_ + c0)*P_ + p0 + px;
    #pragma unroll
    for (int j=0;j<64;++j){ float v = u2f(xb[(size_t)j*P_]); vals[j] = v; ss += v*v; }
  }
  sred[ch][px] = ss;
  __syncthreads();
  float invn = 1.f / fmaxf(sqrtf(sred[0][px] + sred[1][px]), 1e-12f);
  #pragma unroll
  for (int j=0;j<64;++j) tile[c0+j][px] = f2u(vals[j]*invn);
  __syncthreads();

  // xnT[n][p][c]: 128 rows(px) x 64 u32 — coalesced 256B/wave
  unsigned* xt = (unsigned*)(xnT + ((size_t)n*P_ + p0)*C_);
  #pragma unroll
  for (int it=0;it<32;++it){
    int i = t + it*256;
    int row = i>>6, cw = i&63;
    unsigned pk = (unsigned)tile[2*cw][row] | ((unsigned)tile[2*cw+1][row] << 16);
    xt[row*64 + cw] = pk;
  }
  // xnC[n][c][p]: 128 rows(c) x 64 u32 — coalesced
  unsigned* xq = (unsigned*)(xnC + (size_t)n*C_*P_ + p0);
  #pragma unroll
  for (int it=0;it<32;++it){
    int i = t + it*256;
    int row = i>>6, pw = i&63;
    unsigned pk = *(const unsigned*)&tile[row][2*pw];
    xq[(size_t)row*(P_/2) + pw] = pk;
  }
}

// ---------- K2: fused 512-row MFMA GEMM + softmax + region-sum partials (R7-proven) ----------
// grid (NB_=72, N_=32), 4 waves. Wave w owns rows [w*128, w*128+128).
__global__ __launch_bounds__(256, 3) void k_gemm(const bf16* __restrict__ Wall,
                                                 const bf16* __restrict__ xnT,
                                                 unsigned short* __restrict__ a,
                                                 float* __restrict__ salPart){
  __shared__ __align__(16) char smem[320*34*4];            // 43520 B; reused as appS
  float (*ldsL)[34] = (float(*)[34])smem;                  // [320][34]
  unsigned short (*appS)[36] = (unsigned short(*)[36])smem;// [192][36] = 13824 B
  __shared__ float redA[32][8];
  __shared__ float redB[32][8];
  __shared__ __align__(16) unsigned short a_tile[K_*32];
  int n = blockIdx.y, pb = blockIdx.x;
  int p0 = pb*32;
  int t = threadIdx.x, wv = t>>6, l = t&63;

  int mrow = l&15, quad = l>>4;
  const bf16* Abase = Wall + ((size_t)(wv*128 + mrow))*C_ + quad*8;
  const bf16* Bbase = xnT + ((size_t)n*P_ + p0 + mrow)*C_ + quad*8;

  f32x4 acc[8][2];
  #pragma unroll
  for (int rt=0;rt<8;++rt){ acc[rt][0] = (f32x4){0,0,0,0}; acc[rt][1] = (f32x4){0,0,0,0}; }

  #pragma unroll
  for (int k0=0;k0<C_;k0+=32){
    bf16x8 b0 = *(const bf16x8*)(Bbase + k0);
    bf16x8 b1 = *(const bf16x8*)(Bbase + 16*C_ + k0);
    #pragma unroll
    for (int rt=0;rt<8;++rt){
      bf16x8 af = *(const bf16x8*)(Abase + (size_t)rt*16*C_ + k0);
      acc[rt][0] = __builtin_amdgcn_mfma_f32_16x16x32_bf16(af, b0, acc[rt][0], 0,0,0);
      acc[rt][1] = __builtin_amdgcn_mfma_f32_16x16x32_bf16(af, b1, acc[rt][1], 0,0,0);
    }
  }
  // C/D: col = lane&15, row = quad*4 + reg. Rows <320 -> LDS; app rows stay in regs.
  #pragma unroll
  for (int rt=0;rt<8;++rt){
    int row0 = wv*128 + rt*16;
    if (row0 < 320){
      #pragma unroll
      for (int ct=0;ct<2;++ct)
        #pragma unroll
        for (int r=0;r<4;++r)
          ldsL[row0 + quad*4 + r][ct*16 + mrow] = acc[rt][ct][r];
    }
  }
  __syncthreads();

  // ---- softmax: thread t -> pixel px = t&31, cluster group g2 = t>>5 ----
  int px = t&31, g2 = t>>5;
  float sc[8];
  #pragma unroll
  for (int kk=0;kk<8;++kk) sc[kk] = ldsL[g2*8+kk][px];
  float pm = sc[0];
  #pragma unroll
  for (int kk=1;kk<8;++kk) pm = fmaxf(pm, sc[kk]);
  redA[px][g2] = pm;
  __syncthreads();
  float m = redA[px][0];
  #pragma unroll
  for (int i=1;i<8;++i) m = fmaxf(m, redA[px][i]);
  float ps = 0.f;
  #pragma unroll
  for (int kk=0;kk<8;++kk) ps += __expf(sc[kk]-m);
  redB[px][g2] = ps;
  __syncthreads();
  float Z = 0.f;
  #pragma unroll
  for (int i=0;i<8;++i) Z += redB[px][i];
  float invZ = 1.f / Z;

  #pragma unroll
  for (int kk=0;kk<8;++kk){
    int k = g2*8 + kk;
    float s0 = sc[kk];
    float sh0 = ldsL[64 + k*4 + 0][px];
    float sh1 = ldsL[64 + k*4 + 1][px];
    float sh2 = ldsL[64 + k*4 + 2][px];
    float sh3 = ldsL[64 + k*4 + 3][px];
    float m2 = fmaxf(fmaxf(fmaxf(fmaxf(s0, sh0), sh1), sh2), sh3);
    float e0 = __expf(s0-m2);
    float den = e0 + __expf(sh0-m2) + __expf(sh1-m2) + __expf(sh2-m2) + __expf(sh3-m2);
    a_tile[k*32 + px] = f2u(__expf(s0-m)*invZ * (e0/den));
  }
  __syncthreads();   // all ldsL reads done; a_tile complete

  size_t tile = (size_t)n*NB_ + pb;
  *(u16x8*)(a + tile*(K_*32) + t*8) = ((const u16x8*)a_tile)[t];

  // ---- app rows (relu, bf16) -> appS (overlays ldsL) ----
  #pragma unroll
  for (int rt=0;rt<8;++rt){
    int row0 = wv*128 + rt*16;
    if (row0 >= 320){
      int ar0 = row0 - 320 + quad*4;
      #pragma unroll
      for (int ct=0;ct<2;++ct)
        #pragma unroll
        for (int r=0;r<4;++r)
          appS[ar0 + r][ct*16 + mrow] = f2u(fmaxf(acc[rt][ct][r], 0.f));
    }
  }
  __syncthreads();

  // ---- region sums: wave qsel handles a level-slice for its k = t&63 ----
  int qsel = wv, k = t&63;
  int rowbase = (qsel==0) ? k : (qsel==1 ? 64+k : 128+k);
  const unsigned* aps = (const unsigned*)&appS[rowbase][0];
  float racc[8];
  #pragma unroll
  for (int r=0;r<8;++r) racc[r] = 0.f;
  #pragma unroll
  for (int e=0;e<16;++e){
    unsigned pr = aps[e];
    #pragma unroll
    for (int half=0;half<2;++half){
      float v = u2f(half ? (unsigned short)(pr>>16) : (unsigned short)(pr&0xffff));
      int p = p0 + 2*e + half;
      int h = p/48, wc = p - h*48;
      if (qsel == 0){
        racc[0] += v;
      } else if (qsel == 1){
        bool hA = h < 32, hB = h >= 16;
        bool wA = wc < 32, wB = wc >= 16;
        racc[0] += (hA&&wA)?v:0.f; racc[1] += (hA&&wB)?v:0.f;
        racc[2] += (hB&&wA)?v:0.f; racc[3] += (hB&&wB)?v:0.f;
      } else {
        int i0 = (qsel==2)?0:2;
        bool hA = (h>=10*i0-1)&&(h<10*i0+19);
        bool hB = (h>=10*(i0+1)-1)&&(h<10*(i0+1)+19);
        #pragma unroll
        for (int j=0;j<4;++j){
          bool wj = (wc>=10*j-1)&&(wc<10*j+19);
          racc[j]   += (hA&&wj)?v:0.f;
          racc[4+j] += (hB&&wj)?v:0.f;
        }
      }
    }
  }
  float* sp = salPart + tile*(K_*R_) + k*R_;
  if (qsel == 0){
    sp[0] = racc[0];
  } else if (qsel == 1){
    #pragma unroll
    for (int r=0;r<4;++r) sp[1+r] = racc[r];
  } else if (qsel == 2){
    #pragma unroll
    for (int r=0;r<8;++r) sp[5+r] = racc[r];
  } else {
    #pragma unroll
    for (int r=0;r<8;++r) sp[13+r] = racc[r];
  }
}

// ---------- K3: reduce 72 tile partials -> sal[n][k][21] ----------
__global__ __launch_bounds__(256) void k_salred(const float* __restrict__ salPart,
                                                float* __restrict__ sal){
  int tid = blockIdx.x*256 + threadIdx.x;
  if (tid >= N_*K_*R_) return;
  int n = tid / (K_*R_), i = tid - n*(K_*R_);
  const float* sp = salPart + (size_t)n*NB_*(K_*R_) + i;
  float s = 0.f;
  #pragma unroll 8
  for (int b=0;b<NB_;++b) s += sp[(size_t)b*(K_*R_)];
  sal[tid] = s;
}

// ---------- K4: vlad partials via MFMA. Block = (chunk of 256 px, n). ----------
__global__ __launch_bounds__(256) void k_vlad(const bf16* __restrict__ xnC,
                                              const unsigned short* __restrict__ a,
                                              const float* __restrict__ sal,
                                              float* __restrict__ vladPart,
                                              float* __restrict__ sumawPart){
  __shared__ float s_sal[K_][R_];                    // 5376 B
  __shared__ __align__(16) unsigned short awL[8][K_][40];  // 40960 B
  __shared__ float s_part[8][K_];                    // 2048 B
  int chunk = blockIdx.x, n = blockIdx.y, t = threadIdx.x;
  int p0 = chunk*256;
  for (int i=t;i<K_*R_;i+=256) ((float*)s_sal)[i] = sal[(size_t)n*K_*R_ + i];
  __syncthreads();

  #pragma unroll
  for (int pg=0;pg<2;++pg){
    int pxl = (t & 127) + pg*128, khalf = t>>7;
    int pbl = pxl>>5, px = pxl&31;
    int p = p0 + pxl;
    int h = p/48, wc = p - h*48;
    bool h1[2], w1[2], h2[4], w2[4];
    #pragma unroll
    for (int i=0;i<2;++i){ h1[i] = (h>=16*i)&&(h<16*i+32); w1[i] = (wc>=16*i)&&(wc<16*i+32); }
    #pragma unroll
    for (int i=0;i<4;++i){ h2[i] = (h>=10*i-1)&&(h<10*i+19); w2[i] = (wc>=10*i-1)&&(wc<10*i+19); }
    const unsigned short* at = a + ((size_t)(n*NB_ + chunk*8 + pbl)*K_)*32 + px;
    #pragma unroll 4
    for (int kk=0;kk<32;++kk){
      int k = khalf*32 + kk;
      float w = s_sal[k][0];
      #pragma unroll
      for (int i=0;i<2;++i) if (h1[i])
        #pragma unroll
        for (int j=0;j<2;++j) if (w1[j]) w += s_sal[k][1+2*i+j];
      #pragma unroll
      for (int i=0;i<4;++i) if (h2[i])
        #pragma unroll
        for (int j=0;j<4;++j) if (w2[j]) w += s_sal[k][5+4*i+j];
      awL[pbl][k][px] = f2u(u2f(at[k*32]) * w);
    }
  }
  __syncthreads();
  {
    int k = t&63, qr0 = t>>6;
    #pragma unroll
    for (int qq=0;qq<2;++qq){
      int qr = qr0 + qq*4;
      float s = 0.f;
      #pragma unroll 8
      for (int j=0;j<32;++j) s += u2f(awL[qr][k][j]);
      s_part[qr][k] = s;
    }
  }
  __syncthreads();

  int wv = t>>6, l = t&63, mrow = l&15, quad = l>>4;
  f32x4 acc[4][2];
  #pragma unroll
  for (int mt=0;mt<4;++mt){ acc[mt][0] = (f32x4){0,0,0,0}; acc[mt][1] = (f32x4){0,0,0,0}; }
  const bf16* Bb = xnC + ((size_t)n*C_ + wv*32 + mrow)*P_ + p0 + quad*8;
  #pragma unroll
  for (int ks=0;ks<8;++ks){
    bf16x8 b0 = *(const bf16x8*)(Bb + ks*32);
    bf16x8 b1 = *(const bf16x8*)(Bb + (size_t)16*P_ + ks*32);
    #pragma unroll
    for (int mt=0;mt<4;++mt){
      bf16x8 af = *(const bf16x8*)((const bf16*)&awL[ks][mt*16 + mrow][quad*8]);
      acc[mt][0] = __builtin_amdgcn_mfma_f32_16x16x32_bf16(af, b0, acc[mt][0], 0,0,0);
      acc[mt][1] = __builtin_amdgcn_mfma_f32_16x16x32_bf16(af, b1, acc[mt][1], 0,0,0);
    }
  }
  float* vp = vladPart + ((size_t)(n*CH_ + chunk))*(K_*C_);
  #pragma unroll
  for (int mt=0;mt<4;++mt){
    #pragma unroll
    for (int ct=0;ct<2;++ct){
      int c = wv*32 + ct*16 + mrow;
      #pragma unroll
      for (int r=0;r<4;++r){
        int k = mt*16 + quad*4 + r;
        vp[k*C_ + c] = acc[mt][ct][r];
      }
    }
  }
  if (t < K_){
    float s = 0.f;
    #pragma unroll
    for (int qr=0;qr<8;++qr) s += s_part[qr][t];
    sumawPart[((size_t)n*CH_ + chunk)*K_ + t] = s;
  }
}

// ---------- K5: chunk reduce + centroid + intra-norm * clw + global norm + store ----------
__global__ __launch_bounds__(256) void k_final(const float* __restrict__ vladPart,
                                               const float* __restrict__ sumawPart,
                                               const void* __restrict__ cen,
                                               const void* __restrict__ clw,
                                               const void* __restrict__ x,
                                               void* __restrict__ out){
  __shared__ float s_v[K_*C_];
  __shared__ float s_sumaw[K_];
  __shared__ float s_ssk[K_];
  __shared__ float s_scale[K_];
  __shared__ float s_gs;
  int n = blockIdx.x, t = threadIdx.x;
  int f32 = is_f32((const unsigned short*)x);
  if (t < K_){
    float s = 0.f;
    #pragma unroll
    for (int ch=0;ch<CH_;++ch) s += sumawPart[((size_t)n*CH_ + ch)*K_ + t];
    s_sumaw[t] = s;
  }
  __syncthreads();
  const float* vp = vladPart + (size_t)n*CH_*(K_*C_);
  for (int i=t;i<K_*C_;i+=256){
    float v = 0.f;
    #pragma unroll
    for (int ch=0;ch<CH_;++ch) v += vp[(size_t)ch*(K_*C_) + i];
    float cv = f32 ? ((const float*)cen)[i] : b2f(((const bf16*)cen)[i]);
    s_v[i] = v - cv * s_sumaw[i>>7];
  }
  __syncthreads();
  int k = t >> 2, q = t & 3;
  float ss = 0.f;
  for (int mm=0;mm<32;++mm){ float v = s_v[k*C_ + q + 4*mm]; ss += v*v; }
  ss += __shfl_down(ss, 2);
  ss += __shfl_down(ss, 1);
  if (q == 0) s_ssk[k] = ss;
  __syncthreads();
  if (t < K_){
    float cw = f32 ? ((const float*)clw)[t] : b2f(((const bf16*)clw)[t]);
    s_scale[t] = cw / fmaxf(sqrtf(s_ssk[t]), 1e-12f);
  }
  __syncthreads();
  if (t == 0){
    float gss = 0.f;
    for (int kk=0;kk<K_;++kk) gss += s_ssk[kk]*s_scale[kk]*s_scale[kk];
    s_gs = 1.f / fmaxf(sqrtf(gss), 1e-12f);
  }
  __syncthreads();
  float gsc = s_gs;
  if (f32){
    float* op = (float*)out + (size_t)n*K_*C_;
    for (int i=t;i<K_*C_;i+=256) op[i] = s_v[i]*s_scale[i>>7]*gsc;
  } else {
    bf16* op = (bf16*)out + (size_t)n*K_*C_;
    for (int i=t;i<K_*C_;i+=256) op[i] = __float2bfloat16(s_v[i]*s_scale[i>>7]*gsc);
  }
}

extern "C" void kernel_launch(void* const* d_in, const int* in_sizes, int n_in,
                              void* d_out, int out_size, void* d_ws, size_t ws_size,
                              hipStream_t stream){
  const void* x   = d_in[0];
  const void* cen = d_in[1];
  const void* cvw = d_in[2];
  const void* csw = d_in[3];
  const void* caw = d_in[4];
  const void* clw = d_in[5];

  char* ws = (char*)d_ws;
  bf16* Wall  = (bf16*)ws;             ws += (size_t)M_*C_*2;        // 128 KB
  bf16* xnT   = (bf16*)ws;             ws += (size_t)N_*P_*C_*2;     // 18.87 MB
  bf16* xnC   = (bf16*)ws;             ws += (size_t)N_*C_*P_*2;     // 18.87 MB
  unsigned short* a = (unsigned short*)ws;  ws += (size_t)N_*K_*P_*2;// 9.44 MB (tiled)
  float* sal  = (float*)ws;            ws += (size_t)N_*K_*R_*4;     // 0.17 MB
  // union: salPart (12.39 MB, dead after k_salred) overlaid by vladPart (9.44) + sumawPart
  char* un = ws;
  float* salPart   = (float*)un;
  float* vladPart  = (float*)un;
  float* sumawPart = (float*)(un + (size_t)N_*CH_*K_*C_*4);
  ws += (size_t)N_*NB_*K_*R_*4;                                      // 12.39 MB

  k_wall  <<<dim3(M_*C_/256),       256, 0, stream>>>(cvw, csw, caw, x, Wall);
  k_norm  <<<dim3(N_*P_/128),       256, 0, stream>>>(x, xnT, xnC);
  k_gemm  <<<dim3(NB_, N_),         256, 0, stream>>>(Wall, xnT, a, salPart);
  k_salred<<<dim3((N_*K_*R_+255)/256), 256, 0, stream>>>(salPart, sal);
  k_vlad  <<<dim3(CH_, N_),         256, 0, stream>>>(xnC, a, sal, vladPart, sumawPart);
  k_final <<<dim3(N_),              256, 0, stream>>>(vladPart, sumawPart, cen, clw, x, d_out);
}

// Round 10
// 236.106 us; speedup vs baseline: 1.5585x; 1.0019x over previous
//
#include <hip/hip_runtime.h>
#include <hip/hip_bf16.h>

#define N_ 32
#define C_ 128
#define H_ 48
#define W_ 48
#define P_ (H_*W_)   // 2304
#define K_ 64
#define S_ 4
#define L_ 3
#define R_ 21
#define NB_ 72       // P_/32 pixel tiles per image
#define M_ 512       // total logit rows
#define CH_ 9        // vlad chunks (256 px each)

typedef __hip_bfloat16 bf16;
typedef __attribute__((ext_vector_type(8))) short   bf16x8;
typedef __attribute__((ext_vector_type(8))) unsigned short u16x8;
typedef __attribute__((ext_vector_type(4))) float   f32x4;

__device__ __forceinline__ float b2f(bf16 v){ return __bfloat162float(v); }
__device__ __forceinline__ float u2f(unsigned short u){
  union { unsigned i; float f; } v; v.i = ((unsigned)u) << 16; return v.f;
}
__device__ __forceinline__ unsigned short f2u(float f){
  bf16 h = __float2bfloat16(f);
  return *(unsigned short*)&h;
}

// wave-uniform dtype probe: 1 if x is fp32, 0 if bf16 (reads fixed 1024-elem window).
__device__ __forceinline__ int is_f32(const unsigned short* __restrict__ xb){
  int lane = threadIdx.x & 63;
  int w = 0;
  #pragma unroll
  for (int i=0;i<16;++i){
    int e = (xb[lane*16 + i] >> 7) & 0xFF;
    w += (e >= 0x8E) ? 1 : 0;
  }
  unsigned long long b = __ballot(w > 0);
  return __popcll(b) > 32;
}

// ---------- K0: build Wall[512][128] bf16 ----------
__global__ __launch_bounds__(256) void k_wall(const void* __restrict__ cvw, const void* __restrict__ csw,
                                              const void* __restrict__ caw, const void* __restrict__ x,
                                              bf16* __restrict__ Wall){
  int f32 = is_f32((const unsigned short*)x);
  int i = blockIdx.x*256 + threadIdx.x;
  float v;
  if (i < 8192)       v = f32 ? ((const float*)cvw)[i]        : b2f(((const bf16*)cvw)[i]);
  else if (i < 40960) v = f32 ? ((const float*)csw)[i-8192]   : b2f(((const bf16*)csw)[i-8192]);
  else                v = f32 ? ((const float*)caw)[i-40960]  : b2f(((const bf16*)caw)[i-40960]);
  Wall[i] = __float2bfloat16(v);
}

// ---------- K1: L2 norm via LDS transpose; coalesced writes of xnT and xnC ----------
__global__ __launch_bounds__(256) void k_norm(const void* __restrict__ x,
                                              bf16* __restrict__ xnT,
                                              bf16* __restrict__ xnC){
  __shared__ float sred[2][128];
  __shared__ unsigned short tile[128][130];      // [c][px]
  int f32 = is_f32((const unsigned short*)x);
  int bi = blockIdx.x;
  int n = bi / (P_/128), tb = bi % (P_/128);
  int p0 = tb*128;
  int t = threadIdx.x, px = t&127, ch = t>>7, c0 = ch*64;

  float vals[64];
  float ss = 0.f;
  if (f32){
    const float* xb = (const float*)x + ((size_t)n*C_ + c0)*P_ + p0 + px;
    #pragma unroll
    for (int j=0;j<64;++j){ float v = xb[(size_t)j*P_]; vals[j] = v; ss += v*v; }
  } else {
    const unsigned short* xb = (const unsigned short*)x + ((size_t)n*C_ + c0)*P_ + p0 + px;
    #pragma unroll
    for (int j=0;j<64;++j){ float v = u2f(xb[(size_t)j*P_]); vals[j] = v; ss += v*v; }
  }
  sred[ch][px] = ss;
  __syncthreads();
  float invn = 1.f / fmaxf(sqrtf(sred[0][px] + sred[1][px]), 1e-12f);
  #pragma unroll
  for (int j=0;j<64;++j) tile[c0+j][px] = f2u(vals[j]*invn);
  __syncthreads();

  unsigned* xt = (unsigned*)(xnT + ((size_t)n*P_ + p0)*C_);
  #pragma unroll
  for (int it=0;it<32;++it){
    int i = t + it*256;
    int row = i>>6, cw = i&63;
    unsigned pk = (unsigned)tile[2*cw][row] | ((unsigned)tile[2*cw+1][row] << 16);
    xt[row*64 + cw] = pk;
  }
  unsigned* xq = (unsigned*)(xnC + (size_t)n*C_*P_ + p0);
  #pragma unroll
  for (int it=0;it<32;++it){
    int i = t + it*256;
    int row = i>>6, pw = i&63;
    unsigned pk = *(const unsigned*)&tile[row][2*pw];
    xq[(size_t)row*(P_/2) + pw] = pk;
  }
}

// ---------- K2: fused 512-row MFMA GEMM + softmax + region-sum partials; bf16 LDS logits ----------
// grid (NB_=72, N_=32), 4 waves. Wave w owns rows [w*128, w*128+128). 5 blocks/CU.
__global__ __launch_bounds__(256, 5) void k_gemm(const bf16* __restrict__ Wall,
                                                 const bf16* __restrict__ xnT,
                                                 unsigned short* __restrict__ a,
                                                 float* __restrict__ salPart){
  __shared__ __align__(16) char smem[320*36*2];            // 23040 B; reused as appS
  unsigned short (*ldsU)[36] = (unsigned short(*)[36])smem;// [320][36] bf16 logits
  unsigned short (*appS)[36] = (unsigned short(*)[36])smem;// [192][36] overlay
  __shared__ float redA[32][8];
  __shared__ float redB[32][8];
  __shared__ __align__(16) unsigned short a_tile[K_*32];
  int n = blockIdx.y, pb = blockIdx.x;
  int p0 = pb*32;
  int t = threadIdx.x, wv = t>>6, l = t&63;

  int mrow = l&15, quad = l>>4;
  const bf16* Abase = Wall + ((size_t)(wv*128 + mrow))*C_ + quad*8;
  const bf16* Bbase = xnT + ((size_t)n*P_ + p0 + mrow)*C_ + quad*8;

  f32x4 acc[8][2];
  #pragma unroll
  for (int rt=0;rt<8;++rt){ acc[rt][0] = (f32x4){0,0,0,0}; acc[rt][1] = (f32x4){0,0,0,0}; }

  #pragma unroll
  for (int k0=0;k0<C_;k0+=32){
    bf16x8 b0 = *(const bf16x8*)(Bbase + k0);
    bf16x8 b1 = *(const bf16x8*)(Bbase + 16*C_ + k0);
    #pragma unroll
    for (int rt=0;rt<8;++rt){
      bf16x8 af = *(const bf16x8*)(Abase + (size_t)rt*16*C_ + k0);
      acc[rt][0] = __builtin_amdgcn_mfma_f32_16x16x32_bf16(af, b0, acc[rt][0], 0,0,0);
      acc[rt][1] = __builtin_amdgcn_mfma_f32_16x16x32_bf16(af, b1, acc[rt][1], 0,0,0);
    }
  }
  // C/D: col = lane&15, row = quad*4 + reg. Rows <320 -> LDS (bf16); app rows stay in regs.
  #pragma unroll
  for (int rt=0;rt<8;++rt){
    int row0 = wv*128 + rt*16;
    if (row0 < 320){
      #pragma unroll
      for (int ct=0;ct<2;++ct)
        #pragma unroll
        for (int r=0;r<4;++r)
          ldsU[row0 + quad*4 + r][ct*16 + mrow] = f2u(acc[rt][ct][r]);
    }
  }
  __syncthreads();

  // ---- softmax: thread t -> pixel px = t&31, cluster group g2 = t>>5 ----
  int px = t&31, g2 = t>>5;
  float sc[8];
  #pragma unroll
  for (int kk=0;kk<8;++kk) sc[kk] = u2f(ldsU[g2*8+kk][px]);
  float pm = sc[0];
  #pragma unroll
  for (int kk=1;kk<8;++kk) pm = fmaxf(pm, sc[kk]);
  redA[px][g2] = pm;
  __syncthreads();
  float m = redA[px][0];
  #pragma unroll
  for (int i=1;i<8;++i) m = fmaxf(m, redA[px][i]);
  float ps = 0.f;
  #pragma unroll
  for (int kk=0;kk<8;++kk) ps += __expf(sc[kk]-m);
  redB[px][g2] = ps;
  __syncthreads();
  float Z = 0.f;
  #pragma unroll
  for (int i=0;i<8;++i) Z += redB[px][i];
  float invZ = 1.f / Z;

  #pragma unroll
  for (int kk=0;kk<8;++kk){
    int k = g2*8 + kk;
    float s0 = sc[kk];
    float sh0 = u2f(ldsU[64 + k*4 + 0][px]);
    float sh1 = u2f(ldsU[64 + k*4 + 1][px]);
    float sh2 = u2f(ldsU[64 + k*4 + 2][px]);
    float sh3 = u2f(ldsU[64 + k*4 + 3][px]);
    float m2 = fmaxf(fmaxf(fmaxf(fmaxf(s0, sh0), sh1), sh2), sh3);
    float e0 = __expf(s0-m2);
    float den = e0 + __expf(sh0-m2) + __expf(sh1-m2) + __expf(sh2-m2) + __expf(sh3-m2);
    a_tile[k*32 + px] = f2u(__expf(s0-m)*invZ * (e0/den));
  }
  __syncthreads();   // all ldsU reads done; a_tile complete

  size_t tile = (size_t)n*NB_ + pb;
  *(u16x8*)(a + tile*(K_*32) + t*8) = ((const u16x8*)a_tile)[t];

  // ---- app rows (relu, bf16) -> appS (overlays ldsU) ----
  #pragma unroll
  for (int rt=0;rt<8;++rt){
    int row0 = wv*128 + rt*16;
    if (row0 >= 320){
      int ar0 = row0 - 320 + quad*4;
      #pragma unroll
      for (int ct=0;ct<2;++ct)
        #pragma unroll
        for (int r=0;r<4;++r)
          appS[ar0 + r][ct*16 + mrow] = f2u(fmaxf(acc[rt][ct][r], 0.f));
    }
  }
  __syncthreads();

  // ---- region sums: wave qsel handles a level-slice for its k = t&63 ----
  int qsel = wv, k = t&63;
  int rowbase = (qsel==0) ? k : (qsel==1 ? 64+k : 128+k);
  const unsigned* aps = (const unsigned*)&appS[rowbase][0];
  float racc[8];
  #pragma unroll
  for (int r=0;r<8;++r) racc[r] = 0.f;
  #pragma unroll
  for (int e=0;e<16;++e){
    unsigned pr = aps[e];
    #pragma unroll
    for (int half=0;half<2;++half){
      float v = u2f(half ? (unsigned short)(pr>>16) : (unsigned short)(pr&0xffff));
      int p = p0 + 2*e + half;
      int h = p/48, wc = p - h*48;
      if (qsel == 0){
        racc[0] += v;
      } else if (qsel == 1){
        bool hA = h < 32, hB = h >= 16;
        bool wA = wc < 32, wB = wc >= 16;
        racc[0] += (hA&&wA)?v:0.f; racc[1] += (hA&&wB)?v:0.f;
        racc[2] += (hB&&wA)?v:0.f; racc[3] += (hB&&wB)?v:0.f;
      } else {
        int i0 = (qsel==2)?0:2;
        bool hA = (h>=10*i0-1)&&(h<10*i0+19);
        bool hB = (h>=10*(i0+1)-1)&&(h<10*(i0+1)+19);
        #pragma unroll
        for (int j=0;j<4;++j){
          bool wj = (wc>=10*j-1)&&(wc<10*j+19);
          racc[j]   += (hA&&wj)?v:0.f;
          racc[4+j] += (hB&&wj)?v:0.f;
        }
      }
    }
  }
  float* sp = salPart + tile*(K_*R_) + k*R_;
  if (qsel == 0){
    sp[0] = racc[0];
  } else if (qsel == 1){
    #pragma unroll
    for (int r=0;r<4;++r) sp[1+r] = racc[r];
  } else if (qsel == 2){
    #pragma unroll
    for (int r=0;r<8;++r) sp[5+r] = racc[r];
  } else {
    #pragma unroll
    for (int r=0;r<8;++r) sp[13+r] = racc[r];
  }
}

// ---------- K3: reduce 72 tile partials -> sal[n][k][21] ----------
__global__ __launch_bounds__(256) void k_salred(const float* __restrict__ salPart,
                                                float* __restrict__ sal){
  int tid = blockIdx.x*256 + threadIdx.x;
  if (tid >= N_*K_*R_) return;
  int n = tid / (K_*R_), i = tid - n*(K_*R_);
  const float* sp = salPart + (size_t)n*NB_*(K_*R_) + i;
  float s = 0.f;
  #pragma unroll 8
  for (int b=0;b<NB_;++b) s += sp[(size_t)b*(K_*R_)];
  sal[tid] = s;
}

// ---------- K4: vlad partials via MFMA. Block = (chunk of 256 px, n). ----------
__global__ __launch_bounds__(256) void k_vlad(const bf16* __restrict__ xnC,
                                              const unsigned short* __restrict__ a,
                                              const float* __restrict__ sal,
                                              float* __restrict__ vladPart,
                                              float* __restrict__ sumawPart){
  __shared__ float s_sal[K_][R_];                    // 5376 B
  __shared__ __align__(16) unsigned short awL[8][K_][40];  // 40960 B
  __shared__ float s_part[8][K_];                    // 2048 B
  int chunk = blockIdx.x, n = blockIdx.y, t = threadIdx.x;
  int p0 = chunk*256;
  for (int i=t;i<K_*R_;i+=256) ((float*)s_sal)[i] = sal[(size_t)n*K_*R_ + i];
  __syncthreads();

  #pragma unroll
  for (int pg=0;pg<2;++pg){
    int pxl = (t & 127) + pg*128, khalf = t>>7;
    int pbl = pxl>>5, px = pxl&31;
    int p = p0 + pxl;
    int h = p/48, wc = p - h*48;
    bool h1[2], w1[2], h2[4], w2[4];
    #pragma unroll
    for (int i=0;i<2;++i){ h1[i] = (h>=16*i)&&(h<16*i+32); w1[i] = (wc>=16*i)&&(wc<16*i+32); }
    #pragma unroll
    for (int i=0;i<4;++i){ h2[i] = (h>=10*i-1)&&(h<10*i+19); w2[i] = (wc>=10*i-1)&&(wc<10*i+19); }
    const unsigned short* at = a + ((size_t)(n*NB_ + chunk*8 + pbl)*K_)*32 + px;
    #pragma unroll 4
    for (int kk=0;kk<32;++kk){
      int k = khalf*32 + kk;
      float w = s_sal[k][0];
      #pragma unroll
      for (int i=0;i<2;++i) if (h1[i])
        #pragma unroll
        for (int j=0;j<2;++j) if (w1[j]) w += s_sal[k][1+2*i+j];
      #pragma unroll
      for (int i=0;i<4;++i) if (h2[i])
        #pragma unroll
        for (int j=0;j<4;++j) if (w2[j]) w += s_sal[k][5+4*i+j];
      awL[pbl][k][px] = f2u(u2f(at[k*32]) * w);
    }
  }
  __syncthreads();
  {
    int k = t&63, qr0 = t>>6;
    #pragma unroll
    for (int qq=0;qq<2;++qq){
      int qr = qr0 + qq*4;
      float s = 0.f;
      #pragma unroll 8
      for (int j=0;j<32;++j) s += u2f(awL[qr][k][j]);
      s_part[qr][k] = s;
    }
  }
  __syncthreads();

  int wv = t>>6, l = t&63, mrow = l&15, quad = l>>4;
  f32x4 acc[4][2];
  #pragma unroll
  for (int mt=0;mt<4;++mt){ acc[mt][0] = (f32x4){0,0,0,0}; acc[mt][1] = (f32x4){0,0,0,0}; }
  const bf16* Bb = xnC + ((size_t)n*C_ + wv*32 + mrow)*P_ + p0 + quad*8;
  #pragma unroll
  for (int ks=0;ks<8;++ks){
    bf16x8 b0 = *(const bf16x8*)(Bb + ks*32);
    bf16x8 b1 = *(const bf16x8*)(Bb + (size_t)16*P_ + ks*32);
    #pragma unroll
    for (int mt=0;mt<4;++mt){
      bf16x8 af = *(const bf16x8*)((const bf16*)&awL[ks][mt*16 + mrow][quad*8]);
      acc[mt][0] = __builtin_amdgcn_mfma_f32_16x16x32_bf16(af, b0, acc[mt][0], 0,0,0);
      acc[mt][1] = __builtin_amdgcn_mfma_f32_16x16x32_bf16(af, b1, acc[mt][1], 0,0,0);
    }
  }
  float* vp = vladPart + ((size_t)(n*CH_ + chunk))*(K_*C_);
  #pragma unroll
  for (int mt=0;mt<4;++mt){
    #pragma unroll
    for (int ct=0;ct<2;++ct){
      int c = wv*32 + ct*16 + mrow;
      #pragma unroll
      for (int r=0;r<4;++r){
        int k = mt*16 + quad*4 + r;
        vp[k*C_ + c] = acc[mt][ct][r];
      }
    }
  }
  if (t < K_){
    float s = 0.f;
    #pragma unroll
    for (int qr=0;qr<8;++qr) s += s_part[qr][t];
    sumawPart[((size_t)n*CH_ + chunk)*K_ + t] = s;
  }
}

// ---------- K5: parallel chunk reduce + centroid term -> vlad ----------
__global__ __launch_bounds__(256) void k_vred(const float* __restrict__ vladPart,
                                              const float* __restrict__ sumawPart,
                                              const void* __restrict__ cen,
                                              const void* __restrict__ x,
                                              float* __restrict__ vlad){
  int f32 = is_f32((const unsigned short*)x);
  int tid = blockIdx.x*256 + threadIdx.x;       // < N_*K_*C_ = 262144
  int n = tid >> 13;
  int i = tid & 8191;
  int k = i >> 7;
  const float* vp = vladPart + (size_t)n*CH_*(K_*C_) + i;
  float s = 0.f;
  #pragma unroll
  for (int ch=0;ch<CH_;++ch) s += vp[(size_t)ch*(K_*C_)];
  float sw = 0.f;
  #pragma unroll
  for (int ch=0;ch<CH_;++ch) sw += sumawPart[((size_t)n*CH_ + ch)*K_ + k];
  float cv = f32 ? ((const float*)cen)[i] : b2f(((const bf16*)cen)[i]);
  vlad[tid] = s - cv*sw;
}

// ---------- K6: intra-norm * cluster_weights, global L2 norm, store ----------
__global__ __launch_bounds__(256) void k_final(const float* __restrict__ vlad,
                                               const void* __restrict__ clw,
                                               const void* __restrict__ x,
                                               void* __restrict__ out){
  __shared__ float s_v[K_*C_];
  __shared__ float s_ssk[K_];
  __shared__ float s_scale[K_];
  __shared__ float s_gs;
  int n = blockIdx.x, t = threadIdx.x;
  int f32 = is_f32((const unsigned short*)x);
  const float* vp = vlad + (size_t)n*K_*C_;
  for (int i=t;i<K_*C_;i+=256) s_v[i] = vp[i];
  __syncthreads();
  int k = t >> 2, q = t & 3;
  float ss = 0.f;
  for (int mm=0;mm<32;++mm){ float v = s_v[k*C_ + q + 4*mm]; ss += v*v; }
  ss += __shfl_down(ss, 2);
  ss += __shfl_down(ss, 1);
  if (q == 0) s_ssk[k] = ss;
  __syncthreads();
  if (t < K_){
    float cw = f32 ? ((const float*)clw)[t] : b2f(((const bf16*)clw)[t]);
    s_scale[t] = cw / fmaxf(sqrtf(s_ssk[t]), 1e-12f);
  }
  __syncthreads();
  if (t == 0){
    float gss = 0.f;
    for (int kk=0;kk<K_;++kk) gss += s_ssk[kk]*s_scale[kk]*s_scale[kk];
    s_gs = 1.f / fmaxf(sqrtf(gss), 1e-12f);
  }
  __syncthreads();
  float gsc = s_gs;
  if (f32){
    float* op = (float*)out + (size_t)n*K_*C_;
    for (int i=t;i<K_*C_;i+=256) op[i] = s_v[i]*s_scale[i>>7]*gsc;
  } else {
    bf16* op = (bf16*)out + (size_t)n*K_*C_;
    for (int i=t;i<K_*C_;i+=256) op[i] = __float2bfloat16(s_v[i]*s_scale[i>>7]*gsc);
  }
}

extern "C" void kernel_launch(void* const* d_in, const int* in_sizes, int n_in,
                              void* d_out, int out_size, void* d_ws, size_t ws_size,
                              hipStream_t stream){
  const void* x   = d_in[0];
  const void* cen = d_in[1];
  const void* cvw = d_in[2];
  const void* csw = d_in[3];
  const void* caw = d_in[4];
  const void* clw = d_in[5];

  char* ws = (char*)d_ws;
  bf16* Wall  = (bf16*)ws;             ws += (size_t)M_*C_*2;        // 128 KB
  bf16* xnT   = (bf16*)ws;             ws += (size_t)N_*P_*C_*2;     // 18.87 MB
  bf16* xnC   = (bf16*)ws;             ws += (size_t)N_*C_*P_*2;     // 18.87 MB
  char* aBuf  = ws;                    ws += (size_t)N_*K_*P_*2;     // 9.44 MB
  unsigned short* a = (unsigned short*)aBuf;   // dead after k_vlad
  float* vlad = (float*)aBuf;                  // overlay: written by k_vred (1 MB)
  float* sal  = (float*)ws;            ws += (size_t)N_*K_*R_*4;     // 0.17 MB
  // union: salPart (12.39 MB, dead after k_salred) overlaid by vladPart (9.44) + sumawPart
  char* un = ws;
  float* salPart   = (float*)un;
  float* vladPart  = (float*)un;
  float* sumawPart = (float*)(un + (size_t)N_*CH_*K_*C_*4);
  ws += (size_t)N_*NB_*K_*R_*4;                                      // 12.39 MB

  k_wall  <<<dim3(M_*C_/256),       256, 0, stream>>>(cvw, csw, caw, x, Wall);
  k_norm  <<<dim3(N_*P_/128),       256, 0, stream>>>(x, xnT, xnC);
  k_gemm  <<<dim3(NB_, N_),         256, 0, stream>>>(Wall, xnT, a, salPart);
  k_salred<<<dim3((N_*K_*R_+255)/256), 256, 0, stream>>>(salPart, sal);
  k_vlad  <<<dim3(CH_, N_),         256, 0, stream>>>(xnC, a, sal, vladPart, sumawPart);
  k_vred  <<<dim3(N_*K_*C_/256),    256, 0, stream>>>(vladPart, sumawPart, cen, x, vlad);
  k_final <<<dim3(N_),              256, 0, stream>>>(vlad, clw, x, d_out);
}

// Round 11
// 220.633 us; speedup vs baseline: 1.6678x; 1.0701x over previous
//
#include <hip/hip_runtime.h>
#include <hip/hip_bf16.h>

#define N_ 32
#define C_ 128
#define H_ 48
#define W_ 48
#define P_ (H_*W_)   // 2304
#define K_ 64
#define S_ 4
#define L_ 3
#define R_ 21
#define NB_ 72       // P_/32 pixel tiles per image
#define M_ 512       // total logit rows
#define CH_ 9        // vlad chunks (256 px each)

typedef __hip_bfloat16 bf16;
typedef __attribute__((ext_vector_type(8))) short   bf16x8;
typedef __attribute__((ext_vector_type(8))) unsigned short u16x8;
typedef __attribute__((ext_vector_type(4))) float   f32x4;

__device__ __forceinline__ float b2f(bf16 v){ return __bfloat162float(v); }
__device__ __forceinline__ float u2f(unsigned short u){
  union { unsigned i; float f; } v; v.i = ((unsigned)u) << 16; return v.f;
}
__device__ __forceinline__ unsigned short f2u(float f){
  bf16 h = __float2bfloat16(f);
  return *(unsigned short*)&h;
}

// wave-uniform dtype probe: 1 if x is fp32, 0 if bf16 (reads fixed 1024-elem window).
__device__ __forceinline__ int is_f32(const unsigned short* __restrict__ xb){
  int lane = threadIdx.x & 63;
  int w = 0;
  #pragma unroll
  for (int i=0;i<16;++i){
    int e = (xb[lane*16 + i] >> 7) & 0xFF;
    w += (e >= 0x8E) ? 1 : 0;
  }
  unsigned long long b = __ballot(w > 0);
  return __popcll(b) > 32;
}

// ---------- K0: build Wall[512][128] bf16 ----------
__global__ __launch_bounds__(256) void k_wall(const void* __restrict__ cvw, const void* __restrict__ csw,
                                              const void* __restrict__ caw, const void* __restrict__ x,
                                              bf16* __restrict__ Wall){
  int f32 = is_f32((const unsigned short*)x);
  int i = blockIdx.x*256 + threadIdx.x;
  float v;
  if (i < 8192)       v = f32 ? ((const float*)cvw)[i]        : b2f(((const bf16*)cvw)[i]);
  else if (i < 40960) v = f32 ? ((const float*)csw)[i-8192]   : b2f(((const bf16*)csw)[i-8192]);
  else                v = f32 ? ((const float*)caw)[i-40960]  : b2f(((const bf16*)caw)[i-40960]);
  Wall[i] = __float2bfloat16(v);
}

// ---------- K1: L2 norm via LDS transpose; coalesced writes of xnT and xnC ----------
__global__ __launch_bounds__(256) void k_norm(const void* __restrict__ x,
                                              bf16* __restrict__ xnT,
                                              bf16* __restrict__ xnC){
  __shared__ float sred[2][128];
  __shared__ unsigned short tile[128][130];      // [c][px]
  int f32 = is_f32((const unsigned short*)x);
  int bi = blockIdx.x;
  int n = bi / (P_/128), tb = bi % (P_/128);
  int p0 = tb*128;
  int t = threadIdx.x, px = t&127, ch = t>>7, c0 = ch*64;

  float vals[64];
  float ss = 0.f;
  if (f32){
    const float* xb = (const float*)x + ((size_t)n*C_ + c0)*P_ + p0 + px;
    #pragma unroll
    for (int j=0;j<64;++j){ float v = xb[(size_t)j*P_]; vals[j] = v; ss += v*v; }
  } else {
    const unsigned short* xb = (const unsigned short*)x + ((size_t)n*C_ + c0)*P_ + p0 + px;
    #pragma unroll
    for (int j=0;j<64;++j){ float v = u2f(xb[(size_t)j*P_]); vals[j] = v; ss += v*v; }
  }
  sred[ch][px] = ss;
  __syncthreads();
  float invn = 1.f / fmaxf(sqrtf(sred[0][px] + sred[1][px]), 1e-12f);
  #pragma unroll
  for (int j=0;j<64;++j) tile[c0+j][px] = f2u(vals[j]*invn);
  __syncthreads();

  unsigned* xt = (unsigned*)(xnT + ((size_t)n*P_ + p0)*C_);
  #pragma unroll
  for (int it=0;it<32;++it){
    int i = t + it*256;
    int row = i>>6, cw = i&63;
    unsigned pk = (unsigned)tile[2*cw][row] | ((unsigned)tile[2*cw+1][row] << 16);
    xt[row*64 + cw] = pk;
  }
  unsigned* xq = (unsigned*)(xnC + (size_t)n*C_*P_ + p0);
  #pragma unroll
  for (int it=0;it<32;++it){
    int i = t + it*256;
    int row = i>>6, pw = i&63;
    unsigned pk = *(const unsigned*)&tile[row][2*pw];
    xq[(size_t)row*(P_/2) + pw] = pk;
  }
}

// ---------- K2: fused 512-row MFMA GEMM + in-wave softmax + region-sum partials ----------
// grid (NB_=72, N_=32), 4 waves. Wave w owns rows [w*128, w*128+128).
// a layout: [tile][px(32)][k(64)] ushort.
__global__ __launch_bounds__(256, 4) void k_gemm(const bf16* __restrict__ Wall,
                                                 const bf16* __restrict__ xnT,
                                                 unsigned short* __restrict__ a,
                                                 float* __restrict__ salPart){
  __shared__ __align__(16) char smem[320*37*2];            // 23680 B; reused as appS
  unsigned short (*ldsU)[37] = (unsigned short(*)[37])smem;// [320][37] bf16 logits
  unsigned short (*appS)[36] = (unsigned short(*)[36])smem;// [192][36] overlay (13824 B)
  __shared__ __align__(16) unsigned short a_tile[32][K_];  // [px][k], 4096 B
  int n = blockIdx.y, pb = blockIdx.x;
  int p0 = pb*32;
  int t = threadIdx.x, wv = t>>6, l = t&63;

  int mrow = l&15, quad = l>>4;
  const bf16* Abase = Wall + ((size_t)(wv*128 + mrow))*C_ + quad*8;
  const bf16* Bbase = xnT + ((size_t)n*P_ + p0 + mrow)*C_ + quad*8;

  f32x4 acc[8][2];
  #pragma unroll
  for (int rt=0;rt<8;++rt){ acc[rt][0] = (f32x4){0,0,0,0}; acc[rt][1] = (f32x4){0,0,0,0}; }

  #pragma unroll
  for (int k0=0;k0<C_;k0+=32){
    bf16x8 b0 = *(const bf16x8*)(Bbase + k0);
    bf16x8 b1 = *(const bf16x8*)(Bbase + 16*C_ + k0);
    #pragma unroll
    for (int rt=0;rt<8;++rt){
      bf16x8 af = *(const bf16x8*)(Abase + (size_t)rt*16*C_ + k0);
      acc[rt][0] = __builtin_amdgcn_mfma_f32_16x16x32_bf16(af, b0, acc[rt][0], 0,0,0);
      acc[rt][1] = __builtin_amdgcn_mfma_f32_16x16x32_bf16(af, b1, acc[rt][1], 0,0,0);
    }
  }
  // C/D: col = lane&15, row = quad*4 + reg. Rows <320 -> LDS (bf16); app rows stay in regs.
  #pragma unroll
  for (int rt=0;rt<8;++rt){
    int row0 = wv*128 + rt*16;
    if (row0 < 320){
      #pragma unroll
      for (int ct=0;ct<2;++ct)
        #pragma unroll
        for (int r=0;r<4;++r)
          ldsU[row0 + quad*4 + r][ct*16 + mrow] = f2u(acc[rt][ct][r]);
    }
  }
  __syncthreads();

  // ---- softmax: thread t -> pixel px = t>>3, k-group kg = t&7 (8 adjacent lanes per px) ----
  int px = t>>3, kg = t&7;
  float sc[8];
  #pragma unroll
  for (int kk=0;kk<8;++kk) sc[kk] = u2f(ldsU[kg*8+kk][px]);
  float m = sc[0];
  #pragma unroll
  for (int kk=1;kk<8;++kk) m = fmaxf(m, sc[kk]);
  m = fmaxf(m, __shfl_xor(m, 1));
  m = fmaxf(m, __shfl_xor(m, 2));
  m = fmaxf(m, __shfl_xor(m, 4));
  float ps = 0.f;
  #pragma unroll
  for (int kk=0;kk<8;++kk) ps += __expf(sc[kk]-m);
  ps += __shfl_xor(ps, 1);
  ps += __shfl_xor(ps, 2);
  ps += __shfl_xor(ps, 4);
  float invZ = 1.f / ps;

  u16x8 apack;
  #pragma unroll
  for (int kk=0;kk<8;++kk){
    int k = kg*8 + kk;
    float s0 = sc[kk];
    float sh0 = u2f(ldsU[64 + k*4 + 0][px]);
    float sh1 = u2f(ldsU[64 + k*4 + 1][px]);
    float sh2 = u2f(ldsU[64 + k*4 + 2][px]);
    float sh3 = u2f(ldsU[64 + k*4 + 3][px]);
    float m2 = fmaxf(fmaxf(fmaxf(fmaxf(s0, sh0), sh1), sh2), sh3);
    float e0 = __expf(s0-m2);
    float den = e0 + __expf(sh0-m2) + __expf(sh1-m2) + __expf(sh2-m2) + __expf(sh3-m2);
    apack[kk] = f2u(__expf(s0-m)*invZ * (e0/den));
  }
  *(u16x8*)&a_tile[px][kg*8] = apack;   // contiguous 1 KB/wave, conflict-free
  __syncthreads();   // all ldsU reads done; a_tile complete

  // ---- store a tile: straight 16B copy, layout [tile][px][k] ----
  size_t tile = (size_t)n*NB_ + pb;
  *(u16x8*)(a + tile*2048 + t*8) = ((const u16x8*)a_tile)[t];

  // ---- app rows (relu, bf16) -> appS (overlays ldsU) ----
  #pragma unroll
  for (int rt=0;rt<8;++rt){
    int row0 = wv*128 + rt*16;
    if (row0 >= 320){
      int ar0 = row0 - 320 + quad*4;
      #pragma unroll
      for (int ct=0;ct<2;++ct)
        #pragma unroll
        for (int r=0;r<4;++r)
          appS[ar0 + r][ct*16 + mrow] = f2u(fmaxf(acc[rt][ct][r], 0.f));
    }
  }
  __syncthreads();

  // ---- region sums: wave qsel handles a level-slice for its k = t&63 ----
  int qsel = wv, k = t&63;
  int rowbase = (qsel==0) ? k : (qsel==1 ? 64+k : 128+k);
  const unsigned* aps = (const unsigned*)&appS[rowbase][0];
  float racc[8];
  #pragma unroll
  for (int r=0;r<8;++r) racc[r] = 0.f;
  #pragma unroll
  for (int e=0;e<16;++e){
    unsigned pr = aps[e];
    #pragma unroll
    for (int half=0;half<2;++half){
      float v = u2f(half ? (unsigned short)(pr>>16) : (unsigned short)(pr&0xffff));
      int p = p0 + 2*e + half;
      int h = p/48, wc = p - h*48;
      if (qsel == 0){
        racc[0] += v;
      } else if (qsel == 1){
        bool hA = h < 32, hB = h >= 16;
        bool wA = wc < 32, wB = wc >= 16;
        racc[0] += (hA&&wA)?v:0.f; racc[1] += (hA&&wB)?v:0.f;
        racc[2] += (hB&&wA)?v:0.f; racc[3] += (hB&&wB)?v:0.f;
      } else {
        int i0 = (qsel==2)?0:2;
        bool hA = (h>=10*i0-1)&&(h<10*i0+19);
        bool hB = (h>=10*(i0+1)-1)&&(h<10*(i0+1)+19);
        #pragma unroll
        for (int j=0;j<4;++j){
          bool wj = (wc>=10*j-1)&&(wc<10*j+19);
          racc[j]   += (hA&&wj)?v:0.f;
          racc[4+j] += (hB&&wj)?v:0.f;
        }
      }
    }
  }
  float* sp = salPart + tile*(K_*R_) + k*R_;
  if (qsel == 0){
    sp[0] = racc[0];
  } else if (qsel == 1){
    #pragma unroll
    for (int r=0;r<4;++r) sp[1+r] = racc[r];
  } else if (qsel == 2){
    #pragma unroll
    for (int r=0;r<8;++r) sp[5+r] = racc[r];
  } else {
    #pragma unroll
    for (int r=0;r<8;++r) sp[13+r] = racc[r];
  }
}

// ---------- K3: reduce 72 tile partials -> sal[n][k][21] ----------
__global__ __launch_bounds__(256) void k_salred(const float* __restrict__ salPart,
                                                float* __restrict__ sal){
  int tid = blockIdx.x*256 + threadIdx.x;
  if (tid >= N_*K_*R_) return;
  int n = tid / (K_*R_), i = tid - n*(K_*R_);
  const float* sp = salPart + (size_t)n*NB_*(K_*R_) + i;
  float s = 0.f;
  #pragma unroll 8
  for (int b=0;b<NB_;++b) s += sp[(size_t)b*(K_*R_)];
  sal[tid] = s;
}

// ---------- K4: vlad partials via MFMA. Block = (chunk of 256 px, n). ----------
__global__ __launch_bounds__(256) void k_vlad(const bf16* __restrict__ xnC,
                                              const unsigned short* __restrict__ a,
                                              const float* __restrict__ sal,
                                              float* __restrict__ vladPart,
                                              float* __restrict__ sumawPart){
  __shared__ float s_sal[K_][R_];                    // 5376 B
  __shared__ __align__(16) unsigned short awL[8][K_][40];  // 40960 B
  __shared__ float s_part[8][K_];                    // 2048 B
  int chunk = blockIdx.x, n = blockIdx.y, t = threadIdx.x;
  int p0 = chunk*256;
  for (int i=t;i<K_*R_;i+=256) ((float*)s_sal)[i] = sal[(size_t)n*K_*R_ + i];
  __syncthreads();

  #pragma unroll
  for (int pg=0;pg<2;++pg){
    int pxl = (t & 127) + pg*128, khalf = t>>7;
    int pbl = pxl>>5, px = pxl&31;
    int p = p0 + pxl;
    int h = p/48, wc = p - h*48;
    bool h1[2], w1[2], h2[4], w2[4];
    #pragma unroll
    for (int i=0;i<2;++i){ h1[i] = (h>=16*i)&&(h<16*i+32); w1[i] = (wc>=16*i)&&(wc<16*i+32); }
    #pragma unroll
    for (int i=0;i<4;++i){ h2[i] = (h>=10*i-1)&&(h<10*i+19); w2[i] = (wc>=10*i-1)&&(wc<10*i+19); }
    // a layout [tile][px][k]: 32 consecutive k per thread -> 4x u16x8 loads
    const unsigned short* at = a + ((size_t)((n*NB_ + chunk*8 + pbl)*32 + px))*K_ + khalf*32;
    u16x8 av[4];
    #pragma unroll
    for (int q=0;q<4;++q) av[q] = *(const u16x8*)(at + q*8);
    #pragma unroll
    for (int kk=0;kk<32;++kk){
      int k = khalf*32 + kk;
      float w = s_sal[k][0];
      #pragma unroll
      for (int i=0;i<2;++i) if (h1[i])
        #pragma unroll
        for (int j=0;j<2;++j) if (w1[j]) w += s_sal[k][1+2*i+j];
      #pragma unroll
      for (int i=0;i<4;++i) if (h2[i])
        #pragma unroll
        for (int j=0;j<4;++j) if (w2[j]) w += s_sal[k][5+4*i+j];
      awL[pbl][k][px] = f2u(u2f(av[kk>>3][kk&7]) * w);
    }
  }
  __syncthreads();
  {
    int k = t&63, qr0 = t>>6;
    #pragma unroll
    for (int qq=0;qq<2;++qq){
      int qr = qr0 + qq*4;
      float s = 0.f;
      #pragma unroll 8
      for (int j=0;j<32;++j) s += u2f(awL[qr][k][j]);
      s_part[qr][k] = s;
    }
  }
  __syncthreads();

  int wv = t>>6, l = t&63, mrow = l&15, quad = l>>4;
  f32x4 acc[4][2];
  #pragma unroll
  for (int mt=0;mt<4;++mt){ acc[mt][0] = (f32x4){0,0,0,0}; acc[mt][1] = (f32x4){0,0,0,0}; }
  const bf16* Bb = xnC + ((size_t)n*C_ + wv*32 + mrow)*P_ + p0 + quad*8;
  #pragma unroll
  for (int ks=0;ks<8;++ks){
    bf16x8 b0 = *(const bf16x8*)(Bb + ks*32);
    bf16x8 b1 = *(const bf16x8*)(Bb + (size_t)16*P_ + ks*32);
    #pragma unroll
    for (int mt=0;mt<4;++mt){
      bf16x8 af = *(const bf16x8*)((const bf16*)&awL[ks][mt*16 + mrow][quad*8]);
      acc[mt][0] = __builtin_amdgcn_mfma_f32_16x16x32_bf16(af, b0, acc[mt][0], 0,0,0);
      acc[mt][1] = __builtin_amdgcn_mfma_f32_16x16x32_bf16(af, b1, acc[mt][1], 0,0,0);
    }
  }
  float* vp = vladPart + ((size_t)(n*CH_ + chunk))*(K_*C_);
  #pragma unroll
  for (int mt=0;mt<4;++mt){
    #pragma unroll
    for (int ct=0;ct<2;++ct){
      int c = wv*32 + ct*16 + mrow;
      #pragma unroll
      for (int r=0;r<4;++r){
        int k = mt*16 + quad*4 + r;
        vp[k*C_ + c] = acc[mt][ct][r];
      }
    }
  }
  if (t < K_){
    float s = 0.f;
    #pragma unroll
    for (int qr=0;qr<8;++qr) s += s_part[qr][t];
    sumawPart[((size_t)n*CH_ + chunk)*K_ + t] = s;
  }
}

// ---------- K5: parallel chunk reduce + centroid term -> vlad ----------
__global__ __launch_bounds__(256) void k_vred(const float* __restrict__ vladPart,
                                              const float* __restrict__ sumawPart,
                                              const void* __restrict__ cen,
                                              const void* __restrict__ x,
                                              float* __restrict__ vlad){
  int f32 = is_f32((const unsigned short*)x);
  int tid = blockIdx.x*256 + threadIdx.x;       // < N_*K_*C_ = 262144
  int n = tid >> 13;
  int i = tid & 8191;
  int k = i >> 7;
  const float* vp = vladPart + (size_t)n*CH_*(K_*C_) + i;
  float s = 0.f;
  #pragma unroll
  for (int ch=0;ch<CH_;++ch) s += vp[(size_t)ch*(K_*C_)];
  float sw = 0.f;
  #pragma unroll
  for (int ch=0;ch<CH_;++ch) sw += sumawPart[((size_t)n*CH_ + ch)*K_ + k];
  float cv = f32 ? ((const float*)cen)[i] : b2f(((const bf16*)cen)[i]);
  vlad[tid] = s - cv*sw;
}

// ---------- K6: intra-norm * cluster_weights, global L2 norm, store ----------
__global__ __launch_bounds__(256) void k_final(const float* __restrict__ vlad,
                                               const void* __restrict__ clw,
                                               const void* __restrict__ x,
                                               void* __restrict__ out){
  __shared__ float s_v[K_*C_];
  __shared__ float s_ssk[K_];
  __shared__ float s_scale[K_];
  __shared__ float s_gs;
  int n = blockIdx.x, t = threadIdx.x;
  int f32 = is_f32((const unsigned short*)x);
  const float* vp = vlad + (size_t)n*K_*C_;
  for (int i=t;i<K_*C_;i+=256) s_v[i] = vp[i];
  __syncthreads();
  int k = t >> 2, q = t & 3;
  float ss = 0.f;
  for (int mm=0;mm<32;++mm){ float v = s_v[k*C_ + q + 4*mm]; ss += v*v; }
  ss += __shfl_down(ss, 2);
  ss += __shfl_down(ss, 1);
  if (q == 0) s_ssk[k] = ss;
  __syncthreads();
  if (t < K_){
    float cw = f32 ? ((const float*)clw)[t] : b2f(((const bf16*)clw)[t]);
    s_scale[t] = cw / fmaxf(sqrtf(s_ssk[t]), 1e-12f);
  }
  __syncthreads();
  if (t == 0){
    float gss = 0.f;
    for (int kk=0;kk<K_;++kk) gss += s_ssk[kk]*s_scale[kk]*s_scale[kk];
    s_gs = 1.f / fmaxf(sqrtf(gss), 1e-12f);
  }
  __syncthreads();
  float gsc = s_gs;
  if (f32){
    float* op = (float*)out + (size_t)n*K_*C_;
    for (int i=t;i<K_*C_;i+=256) op[i] = s_v[i]*s_scale[i>>7]*gsc;
  } else {
    bf16* op = (bf16*)out + (size_t)n*K_*C_;
    for (int i=t;i<K_*C_;i+=256) op[i] = __float2bfloat16(s_v[i]*s_scale[i>>7]*gsc);
  }
}

extern "C" void kernel_launch(void* const* d_in, const int* in_sizes, int n_in,
                              void* d_out, int out_size, void* d_ws, size_t ws_size,
                              hipStream_t stream){
  const void* x   = d_in[0];
  const void* cen = d_in[1];
  const void* cvw = d_in[2];
  const void* csw = d_in[3];
  const void* caw = d_in[4];
  const void* clw = d_in[5];

  char* ws = (char*)d_ws;
  bf16* Wall  = (bf16*)ws;             ws += (size_t)M_*C_*2;        // 128 KB
  bf16* xnT   = (bf16*)ws;             ws += (size_t)N_*P_*C_*2;     // 18.87 MB
  bf16* xnC   = (bf16*)ws;             ws += (size_t)N_*C_*P_*2;     // 18.87 MB
  char* aBuf  = ws;                    ws += (size_t)N_*K_*P_*2;     // 9.44 MB
  unsigned short* a = (unsigned short*)aBuf;   // dead after k_vlad
  float* vlad = (float*)aBuf;                  // overlay: written by k_vred (1 MB)
  float* sal  = (float*)ws;            ws += (size_t)N_*K_*R_*4;     // 0.17 MB
  char* un = ws;
  float* salPart   = (float*)un;
  float* vladPart  = (float*)un;
  float* sumawPart = (float*)(un + (size_t)N_*CH_*K_*C_*4);
  ws += (size_t)N_*NB_*K_*R_*4;                                      // 12.39 MB

  k_wall  <<<dim3(M_*C_/256),       256, 0, stream>>>(cvw, csw, caw, x, Wall);
  k_norm  <<<dim3(N_*P_/128),       256, 0, stream>>>(x, xnT, xnC);
  k_gemm  <<<dim3(NB_, N_),         256, 0, stream>>>(Wall, xnT, a, salPart);
  k_salred<<<dim3((N_*K_*R_+255)/256), 256, 0, stream>>>(salPart, sal);
  k_vlad  <<<dim3(CH_, N_),         256, 0, stream>>>(xnC, a, sal, vladPart, sumawPart);
  k_vred  <<<dim3(N_*K_*C_/256),    256, 0, stream>>>(vladPart, sumawPart, cen, x, vlad);
  k_final <<<dim3(N_),              256, 0, stream>>>(vlad, clw, x, d_out);
}

// Round 12
// 201.191 us; speedup vs baseline: 1.8290x; 1.0966x over previous
//
#include <hip/hip_runtime.h>
#include <hip/hip_bf16.h>

#define N_ 32
#define C_ 128
#define H_ 48
#define W_ 48
#define P_ (H_*W_)   // 2304
#define K_ 64
#define S_ 4
#define L_ 3
#define R_ 21
#define NB_ 72       // P_/32 pixel tiles per image
#define M_ 512       // total logit rows
#define CH_ 9        // vlad chunks (256 px each)

typedef __hip_bfloat16 bf16;
typedef __attribute__((ext_vector_type(8))) short   bf16x8;
typedef __attribute__((ext_vector_type(8))) unsigned short u16x8;
typedef __attribute__((ext_vector_type(4))) float   f32x4;

__device__ __forceinline__ float b2f(bf16 v){ return __bfloat162float(v); }
__device__ __forceinline__ float u2f(unsigned short u){
  union { unsigned i; float f; } v; v.i = ((unsigned)u) << 16; return v.f;
}
__device__ __forceinline__ unsigned short f2u(float f){
  bf16 h = __float2bfloat16(f);
  return *(unsigned short*)&h;
}

// wave-uniform dtype probe: 1 if x is fp32, 0 if bf16 (reads fixed 1024-elem window).
__device__ __forceinline__ int is_f32(const unsigned short* __restrict__ xb){
  int lane = threadIdx.x & 63;
  int w = 0;
  #pragma unroll
  for (int i=0;i<16;++i){
    int e = (xb[lane*16 + i] >> 7) & 0xFF;
    w += (e >= 0x8E) ? 1 : 0;
  }
  unsigned long long b = __ballot(w > 0);
  return __popcll(b) > 32;
}

// ---------- K0: build WallF in MFMA-fragment order ----------
// frag f = (((wv*8+rt)*4+ks)*64 + lane)*8 + j  <-  row = wv*128+rt*16+(lane&15),
// c = ks*32 + ((lane>>4)&3)*8 + j. Rows: 0-63 score, 64-319 shadow, 320-511 app.
__global__ __launch_bounds__(256) void k_wall(const void* __restrict__ cvw, const void* __restrict__ csw,
                                              const void* __restrict__ caw, const void* __restrict__ x,
                                              bf16* __restrict__ WallF){
  int f32 = is_f32((const unsigned short*)x);
  int i = blockIdx.x*256 + threadIdx.x;          // 0..65535
  int j = i&7, lane = (i>>3)&63, ks = (i>>9)&3, rt = (i>>11)&7, wv = (i>>14)&3;
  int row = wv*128 + rt*16 + (lane&15);
  int c   = ks*32 + ((lane>>4)&3)*8 + j;
  int s = row*C_ + c;
  float v;
  if (s < 8192)       v = f32 ? ((const float*)cvw)[s]        : b2f(((const bf16*)cvw)[s]);
  else if (s < 40960) v = f32 ? ((const float*)csw)[s-8192]   : b2f(((const bf16*)csw)[s-8192]);
  else                v = f32 ? ((const float*)caw)[s-40960]  : b2f(((const bf16*)caw)[s-40960]);
  WallF[i] = __float2bfloat16(v);
}

// ---------- K1: L2 norm -> xnF (k_gemm B-frags) and xnG (k_vlad B-frags), both coalesced ----------
// block = 128 px. xnF chunk o: lane=o&63, half=(o>>6)&1, ks=(o>>7)&3, pbl=(o>>9)&3;
//   elem j: px = pbl*32+half*16+(lane&15), c = ks*32+((lane>>4)&3)*8+j.
// xnG chunk o2: lane, half, wv=(o2>>7)&3, ksl=(o2>>9)&3;
//   elem j: c = wv*32+half*16+(lane&15), p_local = ksl*32+((lane>>4)&3)*8+j.
__global__ __launch_bounds__(256) void k_norm(const void* __restrict__ x,
                                              bf16* __restrict__ xnF,
                                              bf16* __restrict__ xnG){
  __shared__ float sred[2][128];
  __shared__ __align__(16) unsigned short tile[128][136];   // 34816 B, 16B-aligned rows
  int f32 = is_f32((const unsigned short*)x);
  int bi = blockIdx.x;
  int n = bi / (P_/128), tb = bi % (P_/128);
  int p0 = tb*128;
  int t = threadIdx.x, px = t&127, chh = t>>7, c0 = chh*64;

  float vals[64];
  float ss = 0.f;
  if (f32){
    const float* xb = (const float*)x + ((size_t)n*C_ + c0)*P_ + p0 + px;
    #pragma unroll
    for (int j=0;j<64;++j){ float v = xb[(size_t)j*P_]; vals[j] = v; ss += v*v; }
  } else {
    const unsigned short* xb = (const unsigned short*)x + ((size_t)n*C_ + c0)*P_ + p0 + px;
    #pragma unroll
    for (int j=0;j<64;++j){ float v = u2f(xb[(size_t)j*P_]); vals[j] = v; ss += v*v; }
  }
  sred[chh][px] = ss;
  __syncthreads();
  float invn = 1.f / fmaxf(sqrtf(sred[0][px] + sred[1][px]), 1e-12f);
  unsigned short nv[64];
  #pragma unroll
  for (int j=0;j<64;++j) nv[j] = f2u(vals[j]*invn);

  // ---- phase A: tile[c][px] ----
  #pragma unroll
  for (int j=0;j<64;++j) tile[c0+j][px] = nv[j];
  __syncthreads();
  // emit xnG (chunk ch = tb>>1 covers 256 px; this block is half hb)
  {
    int ch = tb>>1, hb = tb&1;
    size_t gbase = ((size_t)(n*CH_ + ch)*8 + hb*4)*512;
    u16x8* out = (u16x8*)xnG;
    #pragma unroll
    for (int it=0;it<8;++it){
      int o2 = t + it*256;
      int lane = o2&63, half = (o2>>6)&1, wvv = (o2>>7)&3, ksl = (o2>>9)&3;
      int c  = wvv*32 + half*16 + (lane&15);
      int pl = ksl*32 + ((lane>>4)&3)*8;
      out[gbase + o2] = *(const u16x8*)&tile[c][pl];
    }
  }
  __syncthreads();
  // ---- phase B: reuse tile as [px][c] ----
  #pragma unroll
  for (int j8=0;j8<8;++j8)
    *(u16x8*)&tile[px][c0 + j8*8] = *(const u16x8*)&nv[j8*8];
  __syncthreads();
  // emit xnF (4 gemm-tiles pb = tb*4 + pbl)
  {
    size_t fbase = (size_t)(n*NB_ + tb*4)*512;
    u16x8* out = (u16x8*)xnF;
    #pragma unroll
    for (int it=0;it<8;++it){
      int o = t + it*256;
      int lane = o&63, half = (o>>6)&1, ks = (o>>7)&3, pbl = (o>>9)&3;
      int pxr = pbl*32 + half*16 + (lane&15);
      int cc  = ks*32 + ((lane>>4)&3)*8;
      out[fbase + o] = *(const u16x8*)&tile[pxr][cc];
    }
  }
}

// ---------- K2: fused 512-row MFMA GEMM + in-wave softmax + region-sum partials ----------
// grid (NB_=72, N_=32), 4 waves. Wave w owns rows [w*128, w*128+128).
// All A/B loads are lane-contiguous fragment loads (1 KB/wave/instr).
__global__ __launch_bounds__(256, 4) void k_gemm(const bf16* __restrict__ WallF,
                                                 const bf16* __restrict__ xnF,
                                                 unsigned short* __restrict__ a,
                                                 float* __restrict__ salPart){
  __shared__ __align__(16) char smem[320*37*2];            // 23680 B; reused as appS
  unsigned short (*ldsU)[37] = (unsigned short(*)[37])smem;// [320][37] bf16 logits
  unsigned short (*appS)[36] = (unsigned short(*)[36])smem;// [192][36] overlay (13824 B)
  __shared__ __align__(16) unsigned short a_tile[32][K_];  // [px][k], 4096 B
  int n = blockIdx.y, pb = blockIdx.x;
  int p0 = pb*32;
  int t = threadIdx.x, wv = t>>6, l = t&63;
  int mrow = l&15, quad = l>>4;

  const bf16* Af = WallF + ((size_t)(wv*8)*4)*512 + l*8;   // + (rt*4+ks)*512
  const bf16* Bf = xnF + (size_t)(n*NB_ + pb)*4096 + l*8;  // + (ks*2+half)*512

  f32x4 acc[8][2];
  #pragma unroll
  for (int rt=0;rt<8;++rt){ acc[rt][0] = (f32x4){0,0,0,0}; acc[rt][1] = (f32x4){0,0,0,0}; }

  #pragma unroll
  for (int ks=0;ks<4;++ks){
    bf16x8 b0 = *(const bf16x8*)(Bf + (ks*2+0)*512);
    bf16x8 b1 = *(const bf16x8*)(Bf + (ks*2+1)*512);
    #pragma unroll
    for (int rt=0;rt<8;++rt){
      bf16x8 af = *(const bf16x8*)(Af + (rt*4+ks)*512);
      acc[rt][0] = __builtin_amdgcn_mfma_f32_16x16x32_bf16(af, b0, acc[rt][0], 0,0,0);
      acc[rt][1] = __builtin_amdgcn_mfma_f32_16x16x32_bf16(af, b1, acc[rt][1], 0,0,0);
    }
  }
  // C/D: col = lane&15, row = quad*4 + reg. Rows <320 -> LDS (bf16); app rows stay in regs.
  #pragma unroll
  for (int rt=0;rt<8;++rt){
    int row0 = wv*128 + rt*16;
    if (row0 < 320){
      #pragma unroll
      for (int ct=0;ct<2;++ct)
        #pragma unroll
        for (int r=0;r<4;++r)
          ldsU[row0 + quad*4 + r][ct*16 + mrow] = f2u(acc[rt][ct][r]);
    }
  }
  __syncthreads();

  // ---- softmax: thread t -> pixel px = t>>3, k-group kg = t&7 ----
  int px = t>>3, kg = t&7;
  float sc[8];
  #pragma unroll
  for (int kk=0;kk<8;++kk) sc[kk] = u2f(ldsU[kg*8+kk][px]);
  float m = sc[0];
  #pragma unroll
  for (int kk=1;kk<8;++kk) m = fmaxf(m, sc[kk]);
  m = fmaxf(m, __shfl_xor(m, 1));
  m = fmaxf(m, __shfl_xor(m, 2));
  m = fmaxf(m, __shfl_xor(m, 4));
  float ps = 0.f;
  #pragma unroll
  for (int kk=0;kk<8;++kk) ps += __expf(sc[kk]-m);
  ps += __shfl_xor(ps, 1);
  ps += __shfl_xor(ps, 2);
  ps += __shfl_xor(ps, 4);
  float invZ = 1.f / ps;

  u16x8 apack;
  #pragma unroll
  for (int kk=0;kk<8;++kk){
    int k = kg*8 + kk;
    float s0 = sc[kk];
    float sh0 = u2f(ldsU[64 + k*4 + 0][px]);
    float sh1 = u2f(ldsU[64 + k*4 + 1][px]);
    float sh2 = u2f(ldsU[64 + k*4 + 2][px]);
    float sh3 = u2f(ldsU[64 + k*4 + 3][px]);
    float m2 = fmaxf(fmaxf(fmaxf(fmaxf(s0, sh0), sh1), sh2), sh3);
    float e0 = __expf(s0-m2);
    float den = e0 + __expf(sh0-m2) + __expf(sh1-m2) + __expf(sh2-m2) + __expf(sh3-m2);
    apack[kk] = f2u(__expf(s0-m)*invZ * (e0/den));
  }
  *(u16x8*)&a_tile[px][kg*8] = apack;
  __syncthreads();   // all ldsU reads done; a_tile complete

  size_t tile = (size_t)n*NB_ + pb;
  *(u16x8*)(a + tile*2048 + t*8) = ((const u16x8*)a_tile)[t];

  // ---- app rows (relu, bf16) -> appS (overlays ldsU) ----
  #pragma unroll
  for (int rt=0;rt<8;++rt){
    int row0 = wv*128 + rt*16;
    if (row0 >= 320){
      int ar0 = row0 - 320 + quad*4;
      #pragma unroll
      for (int ct=0;ct<2;++ct)
        #pragma unroll
        for (int r=0;r<4;++r)
          appS[ar0 + r][ct*16 + mrow] = f2u(fmaxf(acc[rt][ct][r], 0.f));
    }
  }
  __syncthreads();

  // ---- region sums: wave qsel handles a level-slice for its k = t&63 ----
  int qsel = wv, k = t&63;
  int rowbase = (qsel==0) ? k : (qsel==1 ? 64+k : 128+k);
  const unsigned* aps = (const unsigned*)&appS[rowbase][0];
  float racc[8];
  #pragma unroll
  for (int r=0;r<8;++r) racc[r] = 0.f;
  #pragma unroll
  for (int e=0;e<16;++e){
    unsigned pr = aps[e];
    #pragma unroll
    for (int half=0;half<2;++half){
      float v = u2f(half ? (unsigned short)(pr>>16) : (unsigned short)(pr&0xffff));
      int p = p0 + 2*e + half;
      int h = p/48, wc = p - h*48;
      if (qsel == 0){
        racc[0] += v;
      } else if (qsel == 1){
        bool hA = h < 32, hB = h >= 16;
        bool wA = wc < 32, wB = wc >= 16;
        racc[0] += (hA&&wA)?v:0.f; racc[1] += (hA&&wB)?v:0.f;
        racc[2] += (hB&&wA)?v:0.f; racc[3] += (hB&&wB)?v:0.f;
      } else {
        int i0 = (qsel==2)?0:2;
        bool hA = (h>=10*i0-1)&&(h<10*i0+19);
        bool hB = (h>=10*(i0+1)-1)&&(h<10*(i0+1)+19);
        #pragma unroll
        for (int j=0;j<4;++j){
          bool wj = (wc>=10*j-1)&&(wc<10*j+19);
          racc[j]   += (hA&&wj)?v:0.f;
          racc[4+j] += (hB&&wj)?v:0.f;
        }
      }
    }
  }
  float* sp = salPart + tile*(K_*R_) + k*R_;
  if (qsel == 0){
    sp[0] = racc[0];
  } else if (qsel == 1){
    #pragma unroll
    for (int r=0;r<4;++r) sp[1+r] = racc[r];
  } else if (qsel == 2){
    #pragma unroll
    for (int r=0;r<8;++r) sp[5+r] = racc[r];
  } else {
    #pragma unroll
    for (int r=0;r<8;++r) sp[13+r] = racc[r];
  }
}

// ---------- K3: reduce 72 tile partials -> sal[n][k][21] ----------
__global__ __launch_bounds__(256) void k_salred(const float* __restrict__ salPart,
                                                float* __restrict__ sal){
  int tid = blockIdx.x*256 + threadIdx.x;
  if (tid >= N_*K_*R_) return;
  int n = tid / (K_*R_), i = tid - n*(K_*R_);
  const float* sp = salPart + (size_t)n*NB_*(K_*R_) + i;
  float s = 0.f;
  #pragma unroll 8
  for (int b=0;b<NB_;++b) s += sp[(size_t)b*(K_*R_)];
  sal[tid] = s;
}

// ---------- K4: vlad partials via MFMA. Block = (chunk of 256 px, n). ----------
__global__ __launch_bounds__(256) void k_vlad(const bf16* __restrict__ xnG,
                                              const unsigned short* __restrict__ a,
                                              const float* __restrict__ sal,
                                              float* __restrict__ vladPart,
                                              float* __restrict__ sumawPart){
  __shared__ float s_sal[K_][R_];                    // 5376 B
  __shared__ __align__(16) unsigned short awL[8][K_][40];  // 40960 B
  __shared__ float s_part[8][K_];                    // 2048 B
  int chunk = blockIdx.x, n = blockIdx.y, t = threadIdx.x;
  int p0 = chunk*256;
  for (int i=t;i<K_*R_;i+=256) ((float*)s_sal)[i] = sal[(size_t)n*K_*R_ + i];
  __syncthreads();

  #pragma unroll
  for (int pg=0;pg<2;++pg){
    int pxl = (t & 127) + pg*128, khalf = t>>7;
    int pbl = pxl>>5, px = pxl&31;
    int p = p0 + pxl;
    int h = p/48, wc = p - h*48;
    bool h1[2], w1[2], h2[4], w2[4];
    #pragma unroll
    for (int i=0;i<2;++i){ h1[i] = (h>=16*i)&&(h<16*i+32); w1[i] = (wc>=16*i)&&(wc<16*i+32); }
    #pragma unroll
    for (int i=0;i<4;++i){ h2[i] = (h>=10*i-1)&&(h<10*i+19); w2[i] = (wc>=10*i-1)&&(wc<10*i+19); }
    const unsigned short* at = a + ((size_t)((n*NB_ + chunk*8 + pbl)*32 + px))*K_ + khalf*32;
    u16x8 av[4];
    #pragma unroll
    for (int q=0;q<4;++q) av[q] = *(const u16x8*)(at + q*8);
    #pragma unroll
    for (int kk=0;kk<32;++kk){
      int k = khalf*32 + kk;
      float w = s_sal[k][0];
      #pragma unroll
      for (int i=0;i<2;++i) if (h1[i])
        #pragma unroll
        for (int j=0;j<2;++j) if (w1[j]) w += s_sal[k][1+2*i+j];
      #pragma unroll
      for (int i=0;i<4;++i) if (h2[i])
        #pragma unroll
        for (int j=0;j<4;++j) if (w2[j]) w += s_sal[k][5+4*i+j];
      awL[pbl][k][px] = f2u(u2f(av[kk>>3][kk&7]) * w);
    }
  }
  __syncthreads();
  {
    int k = t&63, qr0 = t>>6;
    #pragma unroll
    for (int qq=0;qq<2;++qq){
      int qr = qr0 + qq*4;
      float s = 0.f;
      #pragma unroll 8
      for (int j=0;j<32;++j) s += u2f(awL[qr][k][j]);
      s_part[qr][k] = s;
    }
  }
  __syncthreads();

  int wv = t>>6, l = t&63, mrow = l&15, quad = l>>4;
  f32x4 acc[4][2];
  #pragma unroll
  for (int mt=0;mt<4;++mt){ acc[mt][0] = (f32x4){0,0,0,0}; acc[mt][1] = (f32x4){0,0,0,0}; }
  const bf16* Gf = xnG + (size_t)(n*CH_ + chunk)*32768 + l*8;  // + ((ks*4+wv)*2+half)*512
  #pragma unroll
  for (int ks=0;ks<8;++ks){
    bf16x8 b0 = *(const bf16x8*)(Gf + ((ks*4+wv)*2+0)*512);
    bf16x8 b1 = *(const bf16x8*)(Gf + ((ks*4+wv)*2+1)*512);
    #pragma unroll
    for (int mt=0;mt<4;++mt){
      bf16x8 af = *(const bf16x8*)((const bf16*)&awL[ks][mt*16 + mrow][quad*8]);
      acc[mt][0] = __builtin_amdgcn_mfma_f32_16x16x32_bf16(af, b0, acc[mt][0], 0,0,0);
      acc[mt][1] = __builtin_amdgcn_mfma_f32_16x16x32_bf16(af, b1, acc[mt][1], 0,0,0);
    }
  }
  float* vp = vladPart + ((size_t)(n*CH_ + chunk))*(K_*C_);
  #pragma unroll
  for (int mt=0;mt<4;++mt){
    #pragma unroll
    for (int ct=0;ct<2;++ct){
      int c = wv*32 + ct*16 + mrow;
      #pragma unroll
      for (int r=0;r<4;++r){
        int k = mt*16 + quad*4 + r;
        vp[k*C_ + c] = acc[mt][ct][r];
      }
    }
  }
  if (t < K_){
    float s = 0.f;
    #pragma unroll
    for (int qr=0;qr<8;++qr) s += s_part[qr][t];
    sumawPart[((size_t)n*CH_ + chunk)*K_ + t] = s;
  }
}

// ---------- K5: parallel chunk reduce + centroid term -> vlad ----------
__global__ __launch_bounds__(256) void k_vred(const float* __restrict__ vladPart,
                                              const float* __restrict__ sumawPart,
                                              const void* __restrict__ cen,
                                              const void* __restrict__ x,
                                              float* __restrict__ vlad){
  int f32 = is_f32((const unsigned short*)x);
  int tid = blockIdx.x*256 + threadIdx.x;       // < N_*K_*C_ = 262144
  int n = tid >> 13;
  int i = tid & 8191;
  int k = i >> 7;
  const float* vp = vladPart + (size_t)n*CH_*(K_*C_) + i;
  float s = 0.f;
  #pragma unroll
  for (int ch=0;ch<CH_;++ch) s += vp[(size_t)ch*(K_*C_)];
  float sw = 0.f;
  #pragma unroll
  for (int ch=0;ch<CH_;++ch) sw += sumawPart[((size_t)n*CH_ + ch)*K_ + k];
  float cv = f32 ? ((const float*)cen)[i] : b2f(((const bf16*)cen)[i]);
  vlad[tid] = s - cv*sw;
}

// ---------- K6: intra-norm * cluster_weights, global L2 norm, store ----------
__global__ __launch_bounds__(256) void k_final(const float* __restrict__ vlad,
                                               const void* __restrict__ clw,
                                               const void* __restrict__ x,
                                               void* __restrict__ out){
  __shared__ float s_v[K_*C_];
  __shared__ float s_ssk[K_];
  __shared__ float s_scale[K_];
  __shared__ float s_gs;
  int n = blockIdx.x, t = threadIdx.x;
  int f32 = is_f32((const unsigned short*)x);
  const float* vp = vlad + (size_t)n*K_*C_;
  for (int i=t;i<K_*C_;i+=256) s_v[i] = vp[i];
  __syncthreads();
  int k = t >> 2, q = t & 3;
  float ss = 0.f;
  for (int mm=0;mm<32;++mm){ float v = s_v[k*C_ + q + 4*mm]; ss += v*v; }
  ss += __shfl_down(ss, 2);
  ss += __shfl_down(ss, 1);
  if (q == 0) s_ssk[k] = ss;
  __syncthreads();
  if (t < K_){
    float cw = f32 ? ((const float*)clw)[t] : b2f(((const bf16*)clw)[t]);
    s_scale[t] = cw / fmaxf(sqrtf(s_ssk[t]), 1e-12f);
  }
  __syncthreads();
  if (t == 0){
    float gss = 0.f;
    for (int kk=0;kk<K_;++kk) gss += s_ssk[kk]*s_scale[kk]*s_scale[kk];
    s_gs = 1.f / fmaxf(sqrtf(gss), 1e-12f);
  }
  __syncthreads();
  float gsc = s_gs;
  if (f32){
    float* op = (float*)out + (size_t)n*K_*C_;
    for (int i=t;i<K_*C_;i+=256) op[i] = s_v[i]*s_scale[i>>7]*gsc;
  } else {
    bf16* op = (bf16*)out + (size_t)n*K_*C_;
    for (int i=t;i<K_*C_;i+=256) op[i] = __float2bfloat16(s_v[i]*s_scale[i>>7]*gsc);
  }
}

extern "C" void kernel_launch(void* const* d_in, const int* in_sizes, int n_in,
                              void* d_out, int out_size, void* d_ws, size_t ws_size,
                              hipStream_t stream){
  const void* x   = d_in[0];
  const void* cen = d_in[1];
  const void* cvw = d_in[2];
  const void* csw = d_in[3];
  const void* caw = d_in[4];
  const void* clw = d_in[5];

  char* ws = (char*)d_ws;
  bf16* WallF = (bf16*)ws;             ws += (size_t)M_*C_*2;        // 128 KB
  bf16* xnF   = (bf16*)ws;             ws += (size_t)N_*P_*C_*2;     // 18.87 MB
  bf16* xnG   = (bf16*)ws;             ws += (size_t)N_*C_*P_*2;     // 18.87 MB
  char* aBuf  = ws;                    ws += (size_t)N_*K_*P_*2;     // 9.44 MB
  unsigned short* a = (unsigned short*)aBuf;   // dead after k_vlad
  float* vlad = (float*)aBuf;                  // overlay: written by k_vred (1 MB)
  float* sal  = (float*)ws;            ws += (size_t)N_*K_*R_*4;     // 0.17 MB
  char* un = ws;
  float* salPart   = (float*)un;
  float* vladPart  = (float*)un;
  float* sumawPart = (float*)(un + (size_t)N_*CH_*K_*C_*4);
  ws += (size_t)N_*NB_*K_*R_*4;                                      // 12.39 MB

  k_wall  <<<dim3(M_*C_/256),       256, 0, stream>>>(cvw, csw, caw, x, WallF);
  k_norm  <<<dim3(N_*P_/128),       256, 0, stream>>>(x, xnF, xnG);
  k_gemm  <<<dim3(NB_, N_),         256, 0, stream>>>(WallF, xnF, a, salPart);
  k_salred<<<dim3((N_*K_*R_+255)/256), 256, 0, stream>>>(salPart, sal);
  k_vlad  <<<dim3(CH_, N_),         256, 0, stream>>>(xnG, a, sal, vladPart, sumawPart);
  k_vred  <<<dim3(N_*K_*C_/256),    256, 0, stream>>>(vladPart, sumawPart, cen, x, vlad);
  k_final <<<dim3(N_),              256, 0, stream>>>(vlad, clw, x, d_out);
}